// Round 6
// baseline (732.723 us; speedup 1.0000x reference)
//
#include <hip/hip_runtime.h>

#define N_NODES 100000
#define N_EDGES 1600000
#define F_IN 512
#define F_HID 128
#define F_OUT 64

#define BSH 8                      // bucket = dst >> 8 (256 nodes / bucket)
#define NBUK 391                   // ceil(100000/256)

typedef unsigned int u32;
typedef __attribute__((ext_vector_type(8))) short bf16x8;
typedef __attribute__((ext_vector_type(4))) float f32x4;

__device__ float g7_bf2f(unsigned short u) {
    return __uint_as_float(((unsigned int)u) << 16);
}

__device__ unsigned short g7_f2bf(float f) {
    unsigned int u = __float_as_uint(f);
    u = u + 0x7fffu + ((u >> 16) & 1u);
    return (unsigned short)(u >> 16);
}

// unpack a u32 of 2 packed bf16 -> (lo, hi) floats
__device__ float2 g7_up(unsigned int u) {
    float2 r;
    r.x = __uint_as_float(u << 16);
    r.y = __uint_as_float(u & 0xffff0000u);
    return r;
}

__device__ static inline void g7_gl2lds16(const void* g, void* l) {
    __builtin_amdgcn_global_load_lds(
        (const __attribute__((address_space(1))) u32*)g,
        (__attribute__((address_space(3))) u32*)l, 16, 0, 0);
}

__global__ void GCN_16716012716713_kernel() {}

__global__ void g7_zero(int* p, int n) {
    int i = blockIdx.x * blockDim.x + threadIdx.x;
    if (i < n) p[i] = 0;
}

// edge_index dtype probe: 1=int32, 0=int64 (int64 has all-zero high words).
__global__ void g7_iprobe(const int* raw, int* iflag) {
    __shared__ int s[256];
    int tid = threadIdx.x;
    int f = 0;
    for (int i = tid; i < 1024; i += 256) {
        if (raw[2 * i + 1] != 0) f = 1;
    }
    s[tid] = f;
    __syncthreads();
    for (int off = 128; off > 0; off >>= 1) {
        if (tid < off) s[tid] |= s[tid + off];
        __syncthreads();
    }
    if (tid == 0) iflag[0] = s[0];
}

// float dtype probe on x: 1=bf16, 0=fp32.
__global__ void g7_fprobe(const unsigned int* xw, int* fflag) {
    __shared__ int s[256];
    int tid = threadIdx.x;
    int cnt = 0;
    for (int i = tid; i < 4096; i += 256) {
        unsigned int lo = xw[i] & 0xffffu;
        unsigned int e = (lo >> 7) & 0xffu;
        if (e >= 110u && e <= 140u) cnt = cnt + 1;
    }
    s[tid] = cnt;
    __syncthreads();
    for (int off = 128; off > 0; off >>= 1) {
        if (tid < off) s[tid] += s[tid + off];
        __syncthreads();
    }
    if (tid == 0) fflag[0] = (s[0] > 2048) ? 1 : 0;
}

// pack edge ids to int32 + fused in-degree count (dst half)
__global__ void g7_pack(const int* raw, const int* iflag, int* ei, int* deg) {
    int i = blockIdx.x * blockDim.x + threadIdx.x;
    if (i < 2 * N_EDGES) {
        int v;
        if (iflag[0] == 0) {
            v = raw[2 * i];
        } else {
            v = raw[i];
        }
        ei[i] = v;
        if (i >= N_EDGES) atomicAdd(&deg[v], 1);
    }
}

__global__ void g7_cvt(const void* src, const int* fflag, float* dst, int n) {
    int i = blockIdx.x * blockDim.x + threadIdx.x;
    if (i < n) {
        if (fflag[0] == 1) {
            dst[i] = g7_bf2f(((const unsigned short*)src)[i]);
        } else {
            dst[i] = ((const float*)src)[i];
        }
    }
}

// W1T split: W1Th[n][k] = bf16_hi(W1[k][n]), W1Tl[n][k] = bf16(W1 - hi).
__global__ void g7_w1s(const void* W1, const int* fflag,
                       unsigned short* W1Th, unsigned short* W1Tl) {
    int i = blockIdx.x * blockDim.x + threadIdx.x;
    if (i < F_IN * F_HID) {
        int k = i >> 7;
        int n = i & 127;
        float w;
        if (fflag[0] == 1) {
            w = g7_bf2f(((const unsigned short*)W1)[i]);
        } else {
            w = ((const float*)W1)[i];
        }
        unsigned short hi = g7_f2bf(w);
        unsigned short lo = g7_f2bf(w - g7_bf2f(hi));
        W1Th[n * F_IN + k] = hi;
        W1Tl[n * F_IN + k] = lo;
    }
}

__global__ void g7_dinv(const int* deg, float* dinv) {
    int i = blockIdx.x * blockDim.x + threadIdx.x;
    if (i < N_NODES) {
        dinv[i] = rsqrtf((float)deg[i] + 1.0f);
    }
}

// ---- CSR rowptr build: block-sums -> parallel scan of 391 block sums -> per-block scan ----
__global__ void g7_bsum(const int* deg, int* bsum) {
    __shared__ int s[256];
    int i = blockIdx.x * 256 + threadIdx.x;
    s[threadIdx.x] = (i < N_NODES) ? deg[i] : 0;
    __syncthreads();
    for (int off = 128; off > 0; off >>= 1) {
        if (threadIdx.x < off) s[threadIdx.x] += s[threadIdx.x + off];
        __syncthreads();
    }
    if (threadIdx.x == 0) bsum[blockIdx.x] = s[0];
}

// parallel Hillis-Steele scan of nblk (<=512) block sums, 1 block x 512 thr
__global__ void g7_bscan(const int* bsum, int* boff, int nblk, int* rowptr) {
    __shared__ int s[512];
    int tid = threadIdx.x;
    int v = (tid < nblk) ? bsum[tid] : 0;
    s[tid] = v;
    __syncthreads();
    for (int off = 1; off < 512; off <<= 1) {
        int t = (tid >= off) ? s[tid - off] : 0;
        __syncthreads();
        s[tid] += t;
        __syncthreads();
    }
    if (tid < nblk) boff[tid] = s[tid] - v;   // exclusive
    if (tid == nblk - 1) rowptr[N_NODES] = s[tid];
}

__global__ void g7_scan(const int* deg, const int* boff, int* rowptr) {
    __shared__ int s[256];
    int i = blockIdx.x * 256 + threadIdx.x;
    int v = (i < N_NODES) ? deg[i] : 0;
    s[threadIdx.x] = v;
    __syncthreads();
    for (int off = 1; off < 256; off <<= 1) {
        int t = (threadIdx.x >= off) ? s[threadIdx.x - off] : 0;
        __syncthreads();
        s[threadIdx.x] += t;
        __syncthreads();
    }
    if (i < N_NODES) {
        rowptr[i] = s[threadIdx.x] - v + boff[blockIdx.x];
    }
}

// init per-bucket cursors from rowptr (bucket b starts at node b*256)
__global__ void g7_binit(const int* rowptr, int* bcur) {
    int b = blockIdx.x * blockDim.x + threadIdx.x;
    if (b < NBUK) bcur[b] = rowptr[b << BSH];
}

// ---- partition pass 1: edges -> bucket-contiguous (src,dst) pairs. ----
#define P1_EPT 32
#define P1_TILE (256 * P1_EPT)   // 8192 edges/block, grid 196
__global__ void g7_part1(const int* ei, int* bcur, uint2* part) {
    __shared__ int cnt[NBUK + 1];
    __shared__ int base[NBUK + 1];
    int tid = threadIdx.x;
    long long t0 = (long long)blockIdx.x * P1_TILE;
    for (int i = tid; i < NBUK; i += 256) cnt[i] = 0;
    __syncthreads();
#pragma unroll 4
    for (int r = 0; r < P1_EPT; ++r) {
        long long e = t0 + r * 256 + tid;
        if (e < N_EDGES) {
            int d = ei[N_EDGES + e];
            atomicAdd(&cnt[d >> BSH], 1);
        }
    }
    __syncthreads();
    for (int i = tid; i < NBUK; i += 256) {
        int c = cnt[i];
        base[i] = (c > 0) ? atomicAdd(&bcur[i], c) : 0;
        cnt[i] = 0;                 // reuse as local cursor
    }
    __syncthreads();
#pragma unroll 4
    for (int r = 0; r < P1_EPT; ++r) {
        long long e = t0 + r * 256 + tid;
        if (e < N_EDGES) {
            int s = ei[e];
            int d = ei[N_EDGES + e];
            int bk = d >> BSH;
            int off = atomicAdd(&cnt[bk], 1);
            uint2 p; p.x = (u32)s; p.y = (u32)d;
            part[(long long)base[bk] + off] = p;
        }
    }
}

// ---- partition pass 2: within-bucket exact scatter via LDS cursors. ----
__global__ void g7_part2(const int* rowptr, const uint2* part, int* csr) {
    __shared__ int lcur[256];
    int b = blockIdx.x;
    int tid = threadIdx.x;
    int n0 = b << BSH;
    int n1 = n0 + 256; if (n1 > N_NODES) n1 = N_NODES;
    if (tid < 256) {
        int node = n0 + tid;
        lcur[tid] = (node < N_NODES) ? rowptr[node] : 0;
    }
    __syncthreads();
    int beg = rowptr[n0];
    int end = rowptr[n1];
    for (int j = beg + tid; j < end; j += 512) {
        uint2 p = part[j];
        int pos = atomicAdd(&lcur[p.y - n0], 1);
        csr[pos] = (int)p.x;
    }
}

// ---- GEMM1 split-bf16 MFMA: h1[100000,128] = x @ W1, fp32-class accuracy.
// SINGLE 32KB LDS buffer (A 16K + B 16K), 2 barriers/K-step, 4 blocks/CU
// (m97-style: cross-block wave overlap hides staging latency). A prefetch
// into alternate named reg set issued after stage-barrier (hides under MFMA). ----
__global__ __launch_bounds__(256, 4) void g7_gemm1s(const void* x, const int* fflag,
        const unsigned short* W1Th, const unsigned short* W1Tl, unsigned short* h1b) {
    __shared__ uint4 smv[2048];          // 32 KB: A 16K + B 16K
    char* As = (char*)smv;
    char* Bs = As + 16384;
    int tid = threadIdx.x;
    int m0 = blockIdx.x * 128;
    int w = tid >> 6;
    int lane = tid & 63;
    int wr = w >> 1, wc = w & 1;         // wave grid 2x2
    int la = lane & 15;                  // mfma row/col within 16
    int lk = lane >> 4;                  // mfma k-group (8 bf16 = 16 B)
    int isbf = fflag[0];
    int ar = tid >> 1;                   // A staging: row
    int ah = tid & 1;                    // A staging: k-half (16 elems)

    f32x4 acc[4][4];
#pragma unroll
    for (int i = 0; i < 4; ++i)
#pragma unroll
        for (int j = 0; j < 4; ++j) acc[i][j] = (f32x4){0.f, 0.f, 0.f, 0.f};

    uint4 rA0[4], rA1[4];                // two named A-prefetch sets (rule #20)

    auto loadA = [&](uint4* rA, int k0) {
        int m = m0 + ar;
        if (m >= N_NODES) m = N_NODES - 1;   // dup-read, discarded at store
        if (isbf) {
            const char* s = (const char*)x + ((long long)m * F_IN + k0 + ah * 16) * 2;
            rA[0] = *(const uint4*)s;
            rA[1] = *(const uint4*)(s + 16);
        } else {
            const char* s = (const char*)x + ((long long)m * F_IN + k0 + ah * 16) * 4;
            rA[0] = *(const uint4*)s;
            rA[1] = *(const uint4*)(s + 16);
            rA[2] = *(const uint4*)(s + 32);
            rA[3] = *(const uint4*)(s + 48);
        }
    };

    // convert regs -> hi/lo bf16, swizzled ds_write
    auto writeA = [&](const uint4* rA) {
        float f[16];
        if (isbf) {
            const unsigned short* p = (const unsigned short*)rA;
#pragma unroll
            for (int j = 0; j < 16; ++j) f[j] = g7_bf2f(p[j]);
        } else {
            const float* p = (const float*)rA;
#pragma unroll
            for (int j = 0; j < 16; ++j) f[j] = p[j];
        }
        unsigned int hw[8], lw[8];
#pragma unroll
        for (int j = 0; j < 8; ++j) {
            unsigned short h0 = g7_f2bf(f[2 * j]);
            unsigned short h1v = g7_f2bf(f[2 * j + 1]);
            unsigned short l0 = g7_f2bf(f[2 * j] - g7_bf2f(h0));
            unsigned short l1 = g7_f2bf(f[2 * j + 1] - g7_bf2f(h1v));
            hw[j] = (unsigned int)h0 | ((unsigned int)h1v << 16);
            lw[j] = (unsigned int)l0 | ((unsigned int)l1 << 16);
        }
        int swz = (ar & 7) << 4;
        char* dst = As + ar * 128;
        *(uint4*)(dst + ((ah * 32 + 0) ^ swz))      = make_uint4(hw[0], hw[1], hw[2], hw[3]);
        *(uint4*)(dst + ((ah * 32 + 16) ^ swz))     = make_uint4(hw[4], hw[5], hw[6], hw[7]);
        *(uint4*)(dst + ((64 + ah * 32 + 0) ^ swz)) = make_uint4(lw[0], lw[1], lw[2], lw[3]);
        *(uint4*)(dst + ((64 + ah * 32 + 16) ^ swz))= make_uint4(lw[4], lw[5], lw[6], lw[7]);
    };

    // B-tile: rows n 0..127, 128B = [hi|lo], linear LDS dest + inverse-swizzled source
    auto stageB = [&](int k0) {
#pragma unroll
        for (int p = 0; p < 4; ++p) {
            int nr = w * 32 + p * 8 + (lane >> 3);
            int cp = ((lane & 7) * 16) ^ (((lane >> 3) & 7) << 4);  // source col in [0,128)
            const char* src = (cp < 64)
                ? (const char*)W1Th + (long long)nr * 1024 + k0 * 2 + cp
                : (const char*)W1Tl + (long long)nr * 1024 + k0 * 2 + (cp - 64);
            g7_gl2lds16(src, Bs + (w * 32 + p * 8) * 128);
        }
    };

    auto compute = [&]() {
        bf16x8 a_hi[4], a_lo[4], b_hi[4], b_lo[4];
#pragma unroll
        for (int i = 0; i < 4; ++i) {
            int r = wr * 64 + i * 16 + la;
            int swz = (r & 7) << 4;
            const char* ab = As + r * 128;
            a_hi[i] = *(const bf16x8*)(ab + ((lk * 16) ^ swz));
            a_lo[i] = *(const bf16x8*)(ab + ((64 + lk * 16) ^ swz));
            int n = wc * 64 + i * 16 + la;
            int swzb = (n & 7) << 4;
            const char* bb = Bs + n * 128;
            b_hi[i] = *(const bf16x8*)(bb + ((lk * 16) ^ swzb));
            b_lo[i] = *(const bf16x8*)(bb + ((64 + lk * 16) ^ swzb));
        }
#pragma unroll
        for (int i = 0; i < 4; ++i)
#pragma unroll
            for (int j = 0; j < 4; ++j) {
                acc[i][j] = __builtin_amdgcn_mfma_f32_16x16x32_bf16(
                    a_hi[i], b_hi[j], acc[i][j], 0, 0, 0);
                acc[i][j] = __builtin_amdgcn_mfma_f32_16x16x32_bf16(
                    a_lo[i], b_hi[j], acc[i][j], 0, 0, 0);
                acc[i][j] = __builtin_amdgcn_mfma_f32_16x16x32_bf16(
                    a_hi[i], b_lo[j], acc[i][j], 0, 0, 0);
            }
    };

    loadA(rA0, 0);
#pragma unroll
    for (int kt = 0; kt < 16; kt += 2) {
        // even step: consume rA0, prefetch into rA1
        writeA(rA0);
        stageB(kt * 32);
        __syncthreads();                 // A writes + B stage visible
        loadA(rA1, (kt + 1) * 32);       // issues under compute
        compute();
        __syncthreads();                 // all reads done before next overwrite
        // odd step: consume rA1, prefetch into rA0
        writeA(rA1);
        stageB((kt + 1) * 32);
        __syncthreads();
        if (kt + 2 < 16) loadA(rA0, (kt + 2) * 32);
        compute();
        __syncthreads();
    }

    // epilogue: D row = lk*4+q (m), col = la (n) per 16x16 fragment; bf16 store
#pragma unroll
    for (int i = 0; i < 4; ++i) {
#pragma unroll
        for (int j = 0; j < 4; ++j) {
            int n = wc * 64 + j * 16 + la;
#pragma unroll
            for (int q = 0; q < 4; ++q) {
                int m = m0 + wr * 64 + i * 16 + lk * 4 + q;
                if (m < N_NODES) {
                    h1b[(long long)m * F_HID + n] = g7_f2bf(acc[i][j][q]);
                }
            }
        }
    }
}

// ---- agg1 CSR gather, bf16 table, dual-edge halves + 2-wide unroll. ----
__global__ void g7_agg1(const int* rowptr, const int* csr, const float* dinv,
                        const unsigned short* h1b, const float* b1, float* r1) {
    int node = blockIdx.x * 4 + (threadIdx.x >> 6);
    int lane = threadIdx.x & 63;
    int e = lane >> 5;
    int fl = lane & 31;
    if (node >= N_NODES) return;
    int beg = rowptr[node];
    int end = rowptr[node + 1];
    const uint2* hv = (const uint2*)h1b;   // row = 32 uint2
    float a0 = 0.f, a1 = 0.f, a2 = 0.f, a3 = 0.f;
    int j = beg + e;
    for (; j + 2 < end; j += 4) {
        int s0 = csr[j];
        int s1 = csr[j + 2];
        float w0 = dinv[s0];
        float w1 = dinv[s1];
        uint2 v0 = hv[(long long)s0 * 32 + fl];
        uint2 v1 = hv[(long long)s1 * 32 + fl];
        float2 p0 = g7_up(v0.x), q0 = g7_up(v0.y);
        float2 p1 = g7_up(v1.x), q1 = g7_up(v1.y);
        a0 += p0.x * w0 + p1.x * w1;
        a1 += p0.y * w0 + p1.y * w1;
        a2 += q0.x * w0 + q1.x * w1;
        a3 += q0.y * w0 + q1.y * w1;
    }
    if (j < end) {
        int s0 = csr[j];
        float w0 = dinv[s0];
        uint2 v0 = hv[(long long)s0 * 32 + fl];
        float2 p0 = g7_up(v0.x), q0 = g7_up(v0.y);
        a0 += p0.x * w0;
        a1 += p0.y * w0;
        a2 += q0.x * w0;
        a3 += q0.y * w0;
    }
    float di = dinv[node];
    if (e == 0) {                     // self-loop as an edge with w = dinv[node]
        uint2 vd = hv[(long long)node * 32 + fl];
        float2 pd = g7_up(vd.x), qd = g7_up(vd.y);
        a0 += pd.x * di;
        a1 += pd.y * di;
        a2 += qd.x * di;
        a3 += qd.y * di;
    }
    a0 += __shfl_xor(a0, 32);
    a1 += __shfl_xor(a1, 32);
    a2 += __shfl_xor(a2, 32);
    a3 += __shfl_xor(a3, 32);
    if (e == 0) {
        float4 bb = *(const float4*)(b1 + 4 * fl);
        float r0 = a0 * di + bb.x;
        float r1v = a1 * di + bb.y;
        float r2 = a2 * di + bb.z;
        float r3 = a3 * di + bb.w;
        if (r0 < 0.f) r0 = 0.f;
        if (r1v < 0.f) r1v = 0.f;
        if (r2 < 0.f) r2 = 0.f;
        if (r3 < 0.f) r3 = 0.f;
        float4 o;
        o.x = r0; o.y = r1v; o.z = r2; o.w = r3;
        *(float4*)(r1 + (long long)node * F_HID + 4 * fl) = o;
    }
}

// ---- GEMM2: h2b[100000,64] (bf16) = r1 @ W2f. BM=64, BN=64, BK=32, 256 thr ----
__global__ void g7_gemm2(const float* r1, const float* W2, unsigned short* h2b) {
    __shared__ float Rs[32][68];
    __shared__ float Ws[32][64];
    int tid = threadIdx.x;
    int m0 = blockIdx.x * 64;
    int tx = tid & 15;
    int ty = tid >> 4;
    float acc[4][4];
#pragma unroll
    for (int i = 0; i < 4; ++i) {
#pragma unroll
        for (int j = 0; j < 4; ++j) acc[i][j] = 0.0f;
    }

    for (int k0 = 0; k0 < F_HID; k0 += 32) {
#pragma unroll
        for (int r = 0; r < 8; ++r) {
            int i = r * 256 + tid;
            int kk = i & 31;
            int mm = i >> 5;
            int m = m0 + mm;
            float v = 0.0f;
            if (m < N_NODES) {
                v = r1[(long long)m * F_HID + k0 + kk];
            }
            Rs[kk][mm] = v;
        }
#pragma unroll
        for (int r = 0; r < 8; ++r) {
            int i = r * 256 + tid;
            int wk = i >> 6;
            int wn = i & 63;
            Ws[wk][wn] = W2[(k0 + wk) * F_OUT + wn];
        }
        __syncthreads();
#pragma unroll
        for (int k = 0; k < 32; ++k) {
            float a[4];
            float b[4];
#pragma unroll
            for (int i = 0; i < 4; ++i) a[i] = Rs[k][ty * 4 + i];
#pragma unroll
            for (int j = 0; j < 4; ++j) b[j] = Ws[k][tx * 4 + j];
#pragma unroll
            for (int i = 0; i < 4; ++i) {
#pragma unroll
                for (int j = 0; j < 4; ++j) acc[i][j] += a[i] * b[j];
            }
        }
        __syncthreads();
    }
#pragma unroll
    for (int i = 0; i < 4; ++i) {
        int m = m0 + ty * 4 + i;
        if (m < N_NODES) {
            unsigned int w0 = (unsigned int)g7_f2bf(acc[i][0])
                            | ((unsigned int)g7_f2bf(acc[i][1]) << 16);
            unsigned int w1 = (unsigned int)g7_f2bf(acc[i][2])
                            | ((unsigned int)g7_f2bf(acc[i][3]) << 16);
            uint2 o; o.x = w0; o.y = w1;
            *(uint2*)(h2b + (long long)m * F_OUT + tx * 4) = o;
        }
    }
}

// ---- agg2 CSR gather (bf16 table) + final epilogue, dual-edge halves. ----
__global__ void g7_agg2(const int* rowptr, const int* csr, const float* dinv,
                        const unsigned short* h2b, const float* b2, const int* fflag,
                        void* out) {
    int node = blockIdx.x * 4 + (threadIdx.x >> 6);
    int lane = threadIdx.x & 63;
    int e = lane >> 5;
    int fl = lane & 31;
    if (node >= N_NODES) return;
    int beg = rowptr[node];
    int end = rowptr[node + 1];
    const u32* hv = (const u32*)h2b;   // row = 32 u32
    float a0 = 0.f, a1 = 0.f;
    int j = beg + e;
    for (; j + 2 < end; j += 4) {
        int s0 = csr[j];
        int s1 = csr[j + 2];
        float w0 = dinv[s0];
        float w1 = dinv[s1];
        u32 v0 = hv[(long long)s0 * 32 + fl];
        u32 v1 = hv[(long long)s1 * 32 + fl];
        float2 p0 = g7_up(v0);
        float2 p1 = g7_up(v1);
        a0 += p0.x * w0 + p1.x * w1;
        a1 += p0.y * w0 + p1.y * w1;
    }
    if (j < end) {
        int s0 = csr[j];
        float w0 = dinv[s0];
        u32 v0 = hv[(long long)s0 * 32 + fl];
        float2 p0 = g7_up(v0);
        a0 += p0.x * w0;
        a1 += p0.y * w0;
    }
    float di = dinv[node];
    if (e == 0) {
        u32 vd = hv[(long long)node * 32 + fl];
        float2 pd = g7_up(vd);
        a0 += pd.x * di;
        a1 += pd.y * di;
    }
    a0 += __shfl_xor(a0, 32);
    a1 += __shfl_xor(a1, 32);
    if (e == 0) {
        float v0 = a0 * di + b2[2 * fl];
        float v1 = a1 * di + b2[2 * fl + 1];
        long long oi = (long long)node * F_OUT + 2 * fl;
        if (fflag[0] == 1) {
            u32 o = (u32)g7_f2bf(v0) | ((u32)g7_f2bf(v1) << 16);
            *(u32*)((unsigned short*)out + oi) = o;
        } else {
            float2 o; o.x = v0; o.y = v1;
            *(float2*)((float*)out + oi) = o;
        }
    }
}

extern "C" void kernel_launch(void* const* d_in, const int* in_sizes, int n_in,
                              void* d_out, int out_size, void* d_ws, size_t ws_size,
                              hipStream_t stream) {
    const void* x     = d_in[0];
    const int* ei_raw = (const int*)d_in[1];
    const void* W1    = d_in[2];
    const void* b1    = d_in[3];
    const void* W2    = d_in[4];
    const void* b2    = d_in[5];

    const int NBLK = (N_NODES + 255) / 256;   // 391

    // workspace layout (byte offsets, 16B-aligned):
    char* ws = (char*)d_ws;
    int*   deg    = (int*)(ws + 0);            //    400,000 B
    int*   iflag  = (int*)(ws + 409600);       //          4 B
    int*   fflag  = (int*)(ws + 409616);       //          4 B
    int*   bsum   = (int*)(ws + 409632);       //      1,564 B
    int*   boff   = (int*)(ws + 412800);       //      1,564 B
    int*   bcur   = (int*)(ws + 450560);       //      1,564 B
    float* dinv   = (float*)(ws + 524288);     //    400,000 B
    unsigned short* W1Th = (unsigned short*)(ws + 1048576); // 131,072 B
    unsigned short* W1Tl = (unsigned short*)(ws + 1179648); // 131,072 B
    float* b1f    = (float*)(ws + 1310720);    //        512 B
    float* W2f    = (float*)(ws + 1311232);    //     32,768 B
    float* b2f    = (float*)(ws + 1344000);    //        256 B
    int*   ei     = (int*)(ws + 2097152);      // 12,800,000 B
    int*   rowptr = (int*)(ws + 14897152);     //    400,004 B
    int*   csr    = (int*)(ws + 16777216);     //  6,400,000 B
    unsigned short* h1b = (unsigned short*)(ws + 23177216); // 25,600,000 B
    uint2* part   = (uint2*)(ws + 50331648);   // 12,800,000 B
    float* r1     = (float*)(ws + 74377216);   // 51,200,000 B
    unsigned short* h2b = (unsigned short*)(ws + 125577216); // 12,800,000 B

    g7_zero<<<(N_NODES + 255) / 256, 256, 0, stream>>>(deg, N_NODES);

    g7_iprobe<<<1, 256, 0, stream>>>(ei_raw, iflag);
    g7_fprobe<<<1, 256, 0, stream>>>((const unsigned int*)x, fflag);

    // pack + fused degree count
    g7_pack<<<(2 * N_EDGES + 255) / 256, 256, 0, stream>>>(ei_raw, iflag, ei, deg);

    g7_cvt<<<1, 128, 0, stream>>>(b1, fflag, b1f, F_HID);
    g7_cvt<<<(F_HID * F_OUT + 255) / 256, 256, 0, stream>>>(W2, fflag, W2f, F_HID * F_OUT);
    g7_cvt<<<1, 64, 0, stream>>>(b2, fflag, b2f, F_OUT);
    g7_w1s<<<(F_IN * F_HID + 255) / 256, 256, 0, stream>>>(W1, fflag, W1Th, W1Tl);

    g7_dinv<<<(N_NODES + 255) / 256, 256, 0, stream>>>(deg, dinv);

    // CSR rowptr
    g7_bsum<<<NBLK, 256, 0, stream>>>(deg, bsum);
    g7_bscan<<<1, 512, 0, stream>>>(bsum, boff, NBLK, rowptr);
    g7_scan<<<NBLK, 256, 0, stream>>>(deg, boff, rowptr);

    // two-pass bucket partition (replaces direct scatter)
    g7_binit<<<(NBUK + 255) / 256, 256, 0, stream>>>(rowptr, bcur);
    g7_part1<<<(N_EDGES + P1_TILE - 1) / P1_TILE, 256, 0, stream>>>(ei, bcur, part);
    g7_part2<<<NBUK, 512, 0, stream>>>(rowptr, part, csr);

    // GEMM1: split-bf16 MFMA (fp32-class accuracy), bf16 output table
    g7_gemm1s<<<(N_NODES + 127) / 128, 256, 0, stream>>>(x, fflag, W1Th, W1Tl, h1b);

    g7_agg1<<<N_NODES / 4, 256, 0, stream>>>(rowptr, csr, dinv, h1b, b1f, r1);

    g7_gemm2<<<(N_NODES + 63) / 64, 256, 0, stream>>>(r1, W2f, h2b);

    g7_agg2<<<N_NODES / 4, 256, 0, stream>>>(rowptr, csr, dinv, h2b, b2f, fflag, d_out);
}

// Round 7
// 630.977 us; speedup vs baseline: 1.1613x; 1.1613x over previous
//
#include <hip/hip_runtime.h>

#define N_NODES 100000
#define N_EDGES 1600000
#define F_IN 512
#define F_HID 128
#define F_OUT 64

#define BSH 8                      // bucket = dst >> 8 (256 nodes / bucket)
#define NBUK 391                   // ceil(100000/256)

typedef unsigned int u32;
typedef __attribute__((ext_vector_type(8))) short bf16x8;
typedef __attribute__((ext_vector_type(4))) float f32x4;

__device__ float g7_bf2f(unsigned short u) {
    return __uint_as_float(((unsigned int)u) << 16);
}

__device__ unsigned short g7_f2bf(float f) {
    unsigned int u = __float_as_uint(f);
    u = u + 0x7fffu + ((u >> 16) & 1u);
    return (unsigned short)(u >> 16);
}

// unpack a u32 of 2 packed bf16 -> (lo, hi) floats
__device__ float2 g7_up(unsigned int u) {
    float2 r;
    r.x = __uint_as_float(u << 16);
    r.y = __uint_as_float(u & 0xffff0000u);
    return r;
}

__device__ static inline void g7_gl2lds16(const void* g, void* l) {
    __builtin_amdgcn_global_load_lds(
        (const __attribute__((address_space(1))) u32*)g,
        (__attribute__((address_space(3))) u32*)l, 16, 0, 0);
}

__global__ void GCN_16716012716713_kernel() {}

__global__ void g7_zero(int* p, int n) {
    int i = blockIdx.x * blockDim.x + threadIdx.x;
    if (i < n) p[i] = 0;
}

// edge_index dtype probe: 1=int32, 0=int64 (int64 has all-zero high words).
__global__ void g7_iprobe(const int* raw, int* iflag) {
    __shared__ int s[256];
    int tid = threadIdx.x;
    int f = 0;
    for (int i = tid; i < 1024; i += 256) {
        if (raw[2 * i + 1] != 0) f = 1;
    }
    s[tid] = f;
    __syncthreads();
    for (int off = 128; off > 0; off >>= 1) {
        if (tid < off) s[tid] |= s[tid + off];
        __syncthreads();
    }
    if (tid == 0) iflag[0] = s[0];
}

// float dtype probe on x: 1=bf16, 0=fp32.
__global__ void g7_fprobe(const unsigned int* xw, int* fflag) {
    __shared__ int s[256];
    int tid = threadIdx.x;
    int cnt = 0;
    for (int i = tid; i < 4096; i += 256) {
        unsigned int lo = xw[i] & 0xffffu;
        unsigned int e = (lo >> 7) & 0xffu;
        if (e >= 110u && e <= 140u) cnt = cnt + 1;
    }
    s[tid] = cnt;
    __syncthreads();
    for (int off = 128; off > 0; off >>= 1) {
        if (tid < off) s[tid] += s[tid + off];
        __syncthreads();
    }
    if (tid == 0) fflag[0] = (s[0] > 2048) ? 1 : 0;
}

// pack edge ids to int32 + fused in-degree count (dst half)
__global__ void g7_pack(const int* raw, const int* iflag, int* ei, int* deg) {
    int i = blockIdx.x * blockDim.x + threadIdx.x;
    if (i < 2 * N_EDGES) {
        int v;
        if (iflag[0] == 0) {
            v = raw[2 * i];
        } else {
            v = raw[i];
        }
        ei[i] = v;
        if (i >= N_EDGES) atomicAdd(&deg[v], 1);
    }
}

// fused weight prep: W1 split (65536) + W2 cvt (8192) + b1 (128) + b2 (64)
__global__ void g7_prep(const void* W1, const void* W2, const void* b1, const void* b2,
                        const int* fflag, unsigned short* W1Th, unsigned short* W1Tl,
                        float* W2f, float* b1f, float* b2f) {
    int i = blockIdx.x * blockDim.x + threadIdx.x;
    int isbf = fflag[0];
    if (i < F_IN * F_HID) {
        int k = i >> 7;
        int n = i & 127;
        float w;
        if (isbf == 1) {
            w = g7_bf2f(((const unsigned short*)W1)[i]);
        } else {
            w = ((const float*)W1)[i];
        }
        unsigned short hi = g7_f2bf(w);
        unsigned short lo = g7_f2bf(w - g7_bf2f(hi));
        W1Th[n * F_IN + k] = hi;
        W1Tl[n * F_IN + k] = lo;
    } else if (i < F_IN * F_HID + F_HID * F_OUT) {
        int j = i - F_IN * F_HID;
        W2f[j] = (isbf == 1) ? g7_bf2f(((const unsigned short*)W2)[j])
                             : ((const float*)W2)[j];
    } else if (i < F_IN * F_HID + F_HID * F_OUT + F_HID) {
        int j = i - F_IN * F_HID - F_HID * F_OUT;
        b1f[j] = (isbf == 1) ? g7_bf2f(((const unsigned short*)b1)[j])
                             : ((const float*)b1)[j];
    } else if (i < F_IN * F_HID + F_HID * F_OUT + F_HID + F_OUT) {
        int j = i - F_IN * F_HID - F_HID * F_OUT - F_HID;
        b2f[j] = (isbf == 1) ? g7_bf2f(((const unsigned short*)b2)[j])
                             : ((const float*)b2)[j];
    }
}

__global__ void g7_dinv(const int* deg, float* dinv) {
    int i = blockIdx.x * blockDim.x + threadIdx.x;
    if (i < N_NODES) {
        dinv[i] = rsqrtf((float)deg[i] + 1.0f);
    }
}

// ---- CSR rowptr build: block-sums -> parallel scan of 391 block sums -> per-block scan ----
__global__ void g7_bsum(const int* deg, int* bsum) {
    __shared__ int s[256];
    int i = blockIdx.x * 256 + threadIdx.x;
    s[threadIdx.x] = (i < N_NODES) ? deg[i] : 0;
    __syncthreads();
    for (int off = 128; off > 0; off >>= 1) {
        if (threadIdx.x < off) s[threadIdx.x] += s[threadIdx.x + off];
        __syncthreads();
    }
    if (threadIdx.x == 0) bsum[blockIdx.x] = s[0];
}

// parallel Hillis-Steele scan of nblk (<=512) block sums, 1 block x 512 thr
__global__ void g7_bscan(const int* bsum, int* boff, int nblk, int* rowptr) {
    __shared__ int s[512];
    int tid = threadIdx.x;
    int v = (tid < nblk) ? bsum[tid] : 0;
    s[tid] = v;
    __syncthreads();
    for (int off = 1; off < 512; off <<= 1) {
        int t = (tid >= off) ? s[tid - off] : 0;
        __syncthreads();
        s[tid] += t;
        __syncthreads();
    }
    if (tid < nblk) boff[tid] = s[tid] - v;   // exclusive
    if (tid == nblk - 1) rowptr[N_NODES] = s[tid];
}

__global__ void g7_scan(const int* deg, const int* boff, int* rowptr) {
    __shared__ int s[256];
    int i = blockIdx.x * 256 + threadIdx.x;
    int v = (i < N_NODES) ? deg[i] : 0;
    s[threadIdx.x] = v;
    __syncthreads();
    for (int off = 1; off < 256; off <<= 1) {
        int t = (threadIdx.x >= off) ? s[threadIdx.x - off] : 0;
        __syncthreads();
        s[threadIdx.x] += t;
        __syncthreads();
    }
    if (i < N_NODES) {
        rowptr[i] = s[threadIdx.x] - v + boff[blockIdx.x];
    }
}

// init per-bucket cursors from rowptr (bucket b starts at node b*256)
__global__ void g7_binit(const int* rowptr, int* bcur) {
    int b = blockIdx.x * blockDim.x + threadIdx.x;
    if (b < NBUK) bcur[b] = rowptr[b << BSH];
}

// ---- partition pass 1: edges -> bucket-contiguous (src,dst) pairs. ----
#define P1_EPT 32
#define P1_TILE (256 * P1_EPT)   // 8192 edges/block, grid 196
__global__ void g7_part1(const int* ei, int* bcur, uint2* part) {
    __shared__ int cnt[NBUK + 1];
    __shared__ int base[NBUK + 1];
    int tid = threadIdx.x;
    long long t0 = (long long)blockIdx.x * P1_TILE;
    for (int i = tid; i < NBUK; i += 256) cnt[i] = 0;
    __syncthreads();
#pragma unroll 4
    for (int r = 0; r < P1_EPT; ++r) {
        long long e = t0 + r * 256 + tid;
        if (e < N_EDGES) {
            int d = ei[N_EDGES + e];
            atomicAdd(&cnt[d >> BSH], 1);
        }
    }
    __syncthreads();
    for (int i = tid; i < NBUK; i += 256) {
        int c = cnt[i];
        base[i] = (c > 0) ? atomicAdd(&bcur[i], c) : 0;
        cnt[i] = 0;                 // reuse as local cursor
    }
    __syncthreads();
#pragma unroll 4
    for (int r = 0; r < P1_EPT; ++r) {
        long long e = t0 + r * 256 + tid;
        if (e < N_EDGES) {
            int s = ei[e];
            int d = ei[N_EDGES + e];
            int bk = d >> BSH;
            int off = atomicAdd(&cnt[bk], 1);
            uint2 p; p.x = (u32)s; p.y = (u32)d;
            part[(long long)base[bk] + off] = p;
        }
    }
}

// ---- partition pass 2: within-bucket exact scatter via LDS cursors. ----
__global__ void g7_part2(const int* rowptr, const uint2* part, int* csr) {
    __shared__ int lcur[256];
    int b = blockIdx.x;
    int tid = threadIdx.x;
    int n0 = b << BSH;
    int n1 = n0 + 256; if (n1 > N_NODES) n1 = N_NODES;
    if (tid < 256) {
        int node = n0 + tid;
        lcur[tid] = (node < N_NODES) ? rowptr[node] : 0;
    }
    __syncthreads();
    int beg = rowptr[n0];
    int end = rowptr[n1];
    for (int j = beg + tid; j < end; j += 512) {
        uint2 p = part[j];
        int pos = atomicAdd(&lcur[p.y - n0], 1);
        csr[pos] = (int)p.x;
    }
}

// ---- GEMM1 split-bf16 MFMA: h1[100000,128] = x @ W1, fp32-class accuracy.
// 128x128 tile, 512 thr = 8 waves (2 row-groups x 4 col-groups): wave = 64x32 out,
// acc = 32 AGPR/lane (spill-safe under the 128 unified-reg cap). Double-buffered
// LDS 64KB (round-5 proven sync: prefetch-next / compute-cur / writeA-next / barrier).
// 16 waves/CU target (2 blocks x 8 waves). ----
__global__ __launch_bounds__(512, 4) void g7_gemm1s(const void* x, const int* fflag,
        const unsigned short* W1Th, const unsigned short* W1Tl, unsigned short* h1b) {
    __shared__ uint4 smv[4096];          // 64 KB: [A0 16K][B0 16K][A1 16K][B1 16K]
    char* smc = (char*)smv;
    int tid = threadIdx.x;
    int m0 = blockIdx.x * 128;
    int w = tid >> 6;
    int lane = tid & 63;
    int wr = w >> 2, wc = w & 3;         // wave grid 2x4
    int la = lane & 15;                  // mfma row/col within 16
    int lk = lane >> 4;                  // mfma k-group (8 bf16 = 16 B)
    int isbf = fflag[0];
    int ar = tid >> 2;                   // A staging: row 0..127
    int ah = tid & 3;                    // A staging: 8-elem col chunk

    f32x4 acc[4][2];
#pragma unroll
    for (int i = 0; i < 4; ++i)
#pragma unroll
        for (int j = 0; j < 2; ++j) acc[i][j] = (f32x4){0.f, 0.f, 0.f, 0.f};

    uint4 rA[2];                         // 8 fp32 (2x uint4) or 8 bf16 (1x uint4)

    auto loadA = [&](int k0) {
        int m = m0 + ar;
        if (m >= N_NODES) m = N_NODES - 1;   // dup-read, discarded at store
        if (isbf) {
            const char* s = (const char*)x + ((long long)m * F_IN + k0 + ah * 8) * 2;
            rA[0] = *(const uint4*)s;
        } else {
            const char* s = (const char*)x + ((long long)m * F_IN + k0 + ah * 8) * 4;
            rA[0] = *(const uint4*)s;
            rA[1] = *(const uint4*)(s + 16);
        }
    };

    // convert regs -> hi/lo bf16, swizzled ds_write (8 elems/thread)
    auto writeA = [&](char* As) {
        float f[8];
        if (isbf) {
            const unsigned short* p = (const unsigned short*)&rA[0];
#pragma unroll
            for (int j = 0; j < 8; ++j) f[j] = g7_bf2f(p[j]);
        } else {
            const float* p = (const float*)rA;
#pragma unroll
            for (int j = 0; j < 8; ++j) f[j] = p[j];
        }
        unsigned int hw[4], lw[4];
#pragma unroll
        for (int j = 0; j < 4; ++j) {
            unsigned short h0 = g7_f2bf(f[2 * j]);
            unsigned short h1v = g7_f2bf(f[2 * j + 1]);
            unsigned short l0 = g7_f2bf(f[2 * j] - g7_bf2f(h0));
            unsigned short l1 = g7_f2bf(f[2 * j + 1] - g7_bf2f(h1v));
            hw[j] = (unsigned int)h0 | ((unsigned int)h1v << 16);
            lw[j] = (unsigned int)l0 | ((unsigned int)l1 << 16);
        }
        int swz = (ar & 7) << 4;
        char* dst = As + ar * 128;
        *(uint4*)(dst + ((ah * 16) ^ swz))      = make_uint4(hw[0], hw[1], hw[2], hw[3]);
        *(uint4*)(dst + ((64 + ah * 16) ^ swz)) = make_uint4(lw[0], lw[1], lw[2], lw[3]);
    };

    // B-tile: rows n 0..127 (16 per wave), 128B = [hi|lo] swizzle-permuted,
    // linear LDS dest + inverse-swizzled per-lane global source
    auto stageB = [&](char* Bs, int k0) {
#pragma unroll
        for (int p = 0; p < 2; ++p) {
            int nr = w * 16 + p * 8 + (lane >> 3);
            int cp = ((lane & 7) * 16) ^ (((lane >> 3) & 7) << 4);  // byte col in [0,128)
            const char* src = (cp < 64)
                ? (const char*)W1Th + (long long)nr * 1024 + k0 * 2 + cp
                : (const char*)W1Tl + (long long)nr * 1024 + k0 * 2 + (cp - 64);
            g7_gl2lds16(src, Bs + (w * 16 + p * 8) * 128);
        }
    };

    auto compute = [&](const char* As, const char* Bs) {
        bf16x8 bh[2], bl[2];
#pragma unroll
        for (int j = 0; j < 2; ++j) {
            int n = wc * 32 + j * 16 + la;
            int swzb = (n & 7) << 4;
            const char* bb = Bs + n * 128;
            bh[j] = *(const bf16x8*)(bb + ((lk * 16) ^ swzb));
            bl[j] = *(const bf16x8*)(bb + ((64 + lk * 16) ^ swzb));
        }
#pragma unroll
        for (int i = 0; i < 4; ++i) {
            int r = wr * 64 + i * 16 + la;
            int swz = (r & 7) << 4;
            const char* ab = As + r * 128;
            bf16x8 ah_ = *(const bf16x8*)(ab + ((lk * 16) ^ swz));
            bf16x8 al_ = *(const bf16x8*)(ab + ((64 + lk * 16) ^ swz));
#pragma unroll
            for (int j = 0; j < 2; ++j) {
                acc[i][j] = __builtin_amdgcn_mfma_f32_16x16x32_bf16(
                    ah_, bh[j], acc[i][j], 0, 0, 0);
                acc[i][j] = __builtin_amdgcn_mfma_f32_16x16x32_bf16(
                    al_, bh[j], acc[i][j], 0, 0, 0);
                acc[i][j] = __builtin_amdgcn_mfma_f32_16x16x32_bf16(
                    ah_, bl[j], acc[i][j], 0, 0, 0);
            }
        }
    };

    // prologue: stage K-step 0 into buffer 0
    loadA(0);
    stageB(smc + 16384, 0);
    writeA(smc);
    __syncthreads();                      // drains vmcnt: buf0 ready

    for (int kt = 0; kt < 16; ++kt) {
        char* bc = smc + (kt & 1) * 32768;
        char* bn = smc + ((kt & 1) ^ 1) * 32768;
        if (kt < 15) {                    // issue next-tile loads early (T14)
            loadA((kt + 1) * 32);
            stageB(bn + 16384, (kt + 1) * 32);
        }
        compute(bc, bc + 16384);
        if (kt < 15) writeA(bn);          // convert-late: vmcnt wait lands here
        __syncthreads();
    }

    // epilogue: D row = lk*4+q (m), col = la (n) per 16x16 fragment; bf16 store
#pragma unroll
    for (int i = 0; i < 4; ++i) {
#pragma unroll
        for (int j = 0; j < 2; ++j) {
            int n = wc * 32 + j * 16 + la;
#pragma unroll
            for (int q = 0; q < 4; ++q) {
                int m = m0 + wr * 64 + i * 16 + lk * 4 + q;
                if (m < N_NODES) {
                    h1b[(long long)m * F_HID + n] = g7_f2bf(acc[i][j][q]);
                }
            }
        }
    }
}

// ---- agg1 CSR gather, bf16 table, dual-edge halves + 2-wide unroll. ----
__global__ void g7_agg1(const int* rowptr, const int* csr, const float* dinv,
                        const unsigned short* h1b, const float* b1, float* r1) {
    int node = blockIdx.x * 4 + (threadIdx.x >> 6);
    int lane = threadIdx.x & 63;
    int e = lane >> 5;
    int fl = lane & 31;
    if (node >= N_NODES) return;
    int beg = rowptr[node];
    int end = rowptr[node + 1];
    const uint2* hv = (const uint2*)h1b;   // row = 32 uint2
    float a0 = 0.f, a1 = 0.f, a2 = 0.f, a3 = 0.f;
    int j = beg + e;
    for (; j + 2 < end; j += 4) {
        int s0 = csr[j];
        int s1 = csr[j + 2];
        float w0 = dinv[s0];
        float w1 = dinv[s1];
        uint2 v0 = hv[(long long)s0 * 32 + fl];
        uint2 v1 = hv[(long long)s1 * 32 + fl];
        float2 p0 = g7_up(v0.x), q0 = g7_up(v0.y);
        float2 p1 = g7_up(v1.x), q1 = g7_up(v1.y);
        a0 += p0.x * w0 + p1.x * w1;
        a1 += p0.y * w0 + p1.y * w1;
        a2 += q0.x * w0 + q1.x * w1;
        a3 += q0.y * w0 + q1.y * w1;
    }
    if (j < end) {
        int s0 = csr[j];
        float w0 = dinv[s0];
        uint2 v0 = hv[(long long)s0 * 32 + fl];
        float2 p0 = g7_up(v0.x), q0 = g7_up(v0.y);
        a0 += p0.x * w0;
        a1 += p0.y * w0;
        a2 += q0.x * w0;
        a3 += q0.y * w0;
    }
    float di = dinv[node];
    if (e == 0) {                     // self-loop as an edge with w = dinv[node]
        uint2 vd = hv[(long long)node * 32 + fl];
        float2 pd = g7_up(vd.x), qd = g7_up(vd.y);
        a0 += pd.x * di;
        a1 += pd.y * di;
        a2 += qd.x * di;
        a3 += qd.y * di;
    }
    a0 += __shfl_xor(a0, 32);
    a1 += __shfl_xor(a1, 32);
    a2 += __shfl_xor(a2, 32);
    a3 += __shfl_xor(a3, 32);
    if (e == 0) {
        float4 bb = *(const float4*)(b1 + 4 * fl);
        float r0 = a0 * di + bb.x;
        float r1v = a1 * di + bb.y;
        float r2 = a2 * di + bb.z;
        float r3 = a3 * di + bb.w;
        if (r0 < 0.f) r0 = 0.f;
        if (r1v < 0.f) r1v = 0.f;
        if (r2 < 0.f) r2 = 0.f;
        if (r3 < 0.f) r3 = 0.f;
        float4 o;
        o.x = r0; o.y = r1v; o.z = r2; o.w = r3;
        *(float4*)(r1 + (long long)node * F_HID + 4 * fl) = o;
    }
}

// ---- GEMM2: h2b[100000,64] (bf16) = r1 @ W2f. BM=64, BN=64, BK=32, 256 thr ----
__global__ void g7_gemm2(const float* r1, const float* W2, unsigned short* h2b) {
    __shared__ float Rs[32][68];
    __shared__ float Ws[32][64];
    int tid = threadIdx.x;
    int m0 = blockIdx.x * 64;
    int tx = tid & 15;
    int ty = tid >> 4;
    float acc[4][4];
#pragma unroll
    for (int i = 0; i < 4; ++i) {
#pragma unroll
        for (int j = 0; j < 4; ++j) acc[i][j] = 0.0f;
    }

    for (int k0 = 0; k0 < F_HID; k0 += 32) {
#pragma unroll
        for (int r = 0; r < 8; ++r) {
            int i = r * 256 + tid;
            int kk = i & 31;
            int mm = i >> 5;
            int m = m0 + mm;
            float v = 0.0f;
            if (m < N_NODES) {
                v = r1[(long long)m * F_HID + k0 + kk];
            }
            Rs[kk][mm] = v;
        }
#pragma unroll
        for (int r = 0; r < 8; ++r) {
            int i = r * 256 + tid;
            int wk = i >> 6;
            int wn = i & 63;
            Ws[wk][wn] = W2[(k0 + wk) * F_OUT + wn];
        }
        __syncthreads();
#pragma unroll
        for (int k = 0; k < 32; ++k) {
            float a[4];
            float b[4];
#pragma unroll
            for (int i = 0; i < 4; ++i) a[i] = Rs[k][ty * 4 + i];
#pragma unroll
            for (int j = 0; j < 4; ++j) b[j] = Ws[k][tx * 4 + j];
#pragma unroll
            for (int i = 0; i < 4; ++i) {
#pragma unroll
                for (int j = 0; j < 4; ++j) acc[i][j] += a[i] * b[j];
            }
        }
        __syncthreads();
    }
#pragma unroll
    for (int i = 0; i < 4; ++i) {
        int m = m0 + ty * 4 + i;
        if (m < N_NODES) {
            unsigned int w0 = (unsigned int)g7_f2bf(acc[i][0])
                            | ((unsigned int)g7_f2bf(acc[i][1]) << 16);
            unsigned int w1 = (unsigned int)g7_f2bf(acc[i][2])
                            | ((unsigned int)g7_f2bf(acc[i][3]) << 16);
            uint2 o; o.x = w0; o.y = w1;
            *(uint2*)(h2b + (long long)m * F_OUT + tx * 4) = o;
        }
    }
}

// ---- agg2 CSR gather (bf16 table) + final epilogue, dual-edge halves. ----
__global__ void g7_agg2(const int* rowptr, const int* csr, const float* dinv,
                        const unsigned short* h2b, const float* b2, const int* fflag,
                        void* out) {
    int node = blockIdx.x * 4 + (threadIdx.x >> 6);
    int lane = threadIdx.x & 63;
    int e = lane >> 5;
    int fl = lane & 31;
    if (node >= N_NODES) return;
    int beg = rowptr[node];
    int end = rowptr[node + 1];
    const u32* hv = (const u32*)h2b;   // row = 32 u32
    float a0 = 0.f, a1 = 0.f;
    int j = beg + e;
    for (; j + 2 < end; j += 4) {
        int s0 = csr[j];
        int s1 = csr[j + 2];
        float w0 = dinv[s0];
        float w1 = dinv[s1];
        u32 v0 = hv[(long long)s0 * 32 + fl];
        u32 v1 = hv[(long long)s1 * 32 + fl];
        float2 p0 = g7_up(v0);
        float2 p1 = g7_up(v1);
        a0 += p0.x * w0 + p1.x * w1;
        a1 += p0.y * w0 + p1.y * w1;
    }
    if (j < end) {
        int s0 = csr[j];
        float w0 = dinv[s0];
        u32 v0 = hv[(long long)s0 * 32 + fl];
        float2 p0 = g7_up(v0);
        a0 += p0.x * w0;
        a1 += p0.y * w0;
    }
    float di = dinv[node];
    if (e == 0) {
        u32 vd = hv[(long long)node * 32 + fl];
        float2 pd = g7_up(vd);
        a0 += pd.x * di;
        a1 += pd.y * di;
    }
    a0 += __shfl_xor(a0, 32);
    a1 += __shfl_xor(a1, 32);
    if (e == 0) {
        float v0 = a0 * di + b2[2 * fl];
        float v1 = a1 * di + b2[2 * fl + 1];
        long long oi = (long long)node * F_OUT + 2 * fl;
        if (fflag[0] == 1) {
            u32 o = (u32)g7_f2bf(v0) | ((u32)g7_f2bf(v1) << 16);
            *(u32*)((unsigned short*)out + oi) = o;
        } else {
            float2 o; o.x = v0; o.y = v1;
            *(float2*)((float*)out + oi) = o;
        }
    }
}

extern "C" void kernel_launch(void* const* d_in, const int* in_sizes, int n_in,
                              void* d_out, int out_size, void* d_ws, size_t ws_size,
                              hipStream_t stream) {
    const void* x     = d_in[0];
    const int* ei_raw = (const int*)d_in[1];
    const void* W1    = d_in[2];
    const void* b1    = d_in[3];
    const void* W2    = d_in[4];
    const void* b2    = d_in[5];

    const int NBLK = (N_NODES + 255) / 256;   // 391

    // workspace layout (byte offsets, 16B-aligned):
    char* ws = (char*)d_ws;
    int*   deg    = (int*)(ws + 0);            //    400,000 B
    int*   iflag  = (int*)(ws + 409600);       //          4 B
    int*   fflag  = (int*)(ws + 409616);       //          4 B
    int*   bsum   = (int*)(ws + 409632);       //      1,564 B
    int*   boff   = (int*)(ws + 412800);       //      1,564 B
    int*   bcur   = (int*)(ws + 450560);       //      1,564 B
    float* dinv   = (float*)(ws + 524288);     //    400,000 B
    unsigned short* W1Th = (unsigned short*)(ws + 1048576); // 131,072 B
    unsigned short* W1Tl = (unsigned short*)(ws + 1179648); // 131,072 B
    float* b1f    = (float*)(ws + 1310720);    //        512 B
    float* W2f    = (float*)(ws + 1311232);    //     32,768 B
    float* b2f    = (float*)(ws + 1344000);    //        256 B
    int*   ei     = (int*)(ws + 2097152);      // 12,800,000 B
    int*   rowptr = (int*)(ws + 14897152);     //    400,004 B
    int*   csr    = (int*)(ws + 16777216);     //  6,400,000 B
    unsigned short* h1b = (unsigned short*)(ws + 23177216); // 25,600,000 B
    uint2* part   = (uint2*)(ws + 50331648);   // 12,800,000 B
    float* r1     = (float*)(ws + 74377216);   // 51,200,000 B
    unsigned short* h2b = (unsigned short*)(ws + 125577216); // 12,800,000 B

    g7_zero<<<(N_NODES + 255) / 256, 256, 0, stream>>>(deg, N_NODES);

    g7_iprobe<<<1, 256, 0, stream>>>(ei_raw, iflag);
    g7_fprobe<<<1, 256, 0, stream>>>((const unsigned int*)x, fflag);

    // pack + fused degree count
    g7_pack<<<(2 * N_EDGES + 255) / 256, 256, 0, stream>>>(ei_raw, iflag, ei, deg);

    // fused weight prep (W1 split + W2/b1/b2 cvt)
    const int PREP_N = F_IN * F_HID + F_HID * F_OUT + F_HID + F_OUT;
    g7_prep<<<(PREP_N + 255) / 256, 256, 0, stream>>>(W1, W2, b1, b2, fflag,
                                                      W1Th, W1Tl, W2f, b1f, b2f);

    g7_dinv<<<(N_NODES + 255) / 256, 256, 0, stream>>>(deg, dinv);

    // CSR rowptr
    g7_bsum<<<NBLK, 256, 0, stream>>>(deg, bsum);
    g7_bscan<<<1, 512, 0, stream>>>(bsum, boff, NBLK, rowptr);
    g7_scan<<<NBLK, 256, 0, stream>>>(deg, boff, rowptr);

    // two-pass bucket partition (replaces direct scatter)
    g7_binit<<<(NBUK + 255) / 256, 256, 0, stream>>>(rowptr, bcur);
    g7_part1<<<(N_EDGES + P1_TILE - 1) / P1_TILE, 256, 0, stream>>>(ei, bcur, part);
    g7_part2<<<NBUK, 512, 0, stream>>>(rowptr, part, csr);

    // GEMM1: split-bf16 MFMA (fp32-class accuracy), bf16 output table
    g7_gemm1s<<<(N_NODES + 127) / 128, 512, 0, stream>>>(x, fflag, W1Th, W1Tl, h1b);

    g7_agg1<<<N_NODES / 4, 256, 0, stream>>>(rowptr, csr, dinv, h1b, b1f, r1);

    g7_gemm2<<<(N_NODES + 63) / 64, 256, 0, stream>>>(r1, W2f, h2b);

    g7_agg2<<<N_NODES / 4, 256, 0, stream>>>(rowptr, csr, dinv, h2b, b2f, fflag, d_out);
}

// Round 8
// 609.345 us; speedup vs baseline: 1.2025x; 1.0355x over previous
//
#include <hip/hip_runtime.h>

#define N_NODES 100000
#define N_EDGES 1600000
#define F_IN 512
#define F_HID 128
#define F_OUT 64

#define BSH 8                      // bucket = dst >> 8 (256 nodes / bucket)
#define NBUK 391                   // ceil(100000/256)

typedef unsigned int u32;
typedef __attribute__((ext_vector_type(8))) short bf16x8;
typedef __attribute__((ext_vector_type(4))) float f32x4;

__device__ float g7_bf2f(unsigned short u) {
    return __uint_as_float(((unsigned int)u) << 16);
}

__device__ unsigned short g7_f2bf(float f) {
    unsigned int u = __float_as_uint(f);
    u = u + 0x7fffu + ((u >> 16) & 1u);
    return (unsigned short)(u >> 16);
}

// unpack a u32 of 2 packed bf16 -> (lo, hi) floats
__device__ float2 g7_up(unsigned int u) {
    float2 r;
    r.x = __uint_as_float(u << 16);
    r.y = __uint_as_float(u & 0xffff0000u);
    return r;
}

__device__ static inline void g7_gl2lds16(const void* g, void* l) {
    __builtin_amdgcn_global_load_lds(
        (const __attribute__((address_space(1))) u32*)g,
        (__attribute__((address_space(3))) u32*)l, 16, 0, 0);
}

__global__ void GCN_16716012716713_kernel() {}

__global__ void g7_zero(int* p, int n) {
    int i = blockIdx.x * blockDim.x + threadIdx.x;
    if (i < n) p[i] = 0;
}

// edge_index dtype probe: 1=int32, 0=int64 (int64 has all-zero high words).
__global__ void g7_iprobe(const int* raw, int* iflag) {
    __shared__ int s[256];
    int tid = threadIdx.x;
    int f = 0;
    for (int i = tid; i < 1024; i += 256) {
        if (raw[2 * i + 1] != 0) f = 1;
    }
    s[tid] = f;
    __syncthreads();
    for (int off = 128; off > 0; off >>= 1) {
        if (tid < off) s[tid] |= s[tid + off];
        __syncthreads();
    }
    if (tid == 0) iflag[0] = s[0];
}

// float dtype probe on x: 1=bf16, 0=fp32.
__global__ void g7_fprobe(const unsigned int* xw, int* fflag) {
    __shared__ int s[256];
    int tid = threadIdx.x;
    int cnt = 0;
    for (int i = tid; i < 4096; i += 256) {
        unsigned int lo = xw[i] & 0xffffu;
        unsigned int e = (lo >> 7) & 0xffu;
        if (e >= 110u && e <= 140u) cnt = cnt + 1;
    }
    s[tid] = cnt;
    __syncthreads();
    for (int off = 128; off > 0; off >>= 1) {
        if (tid < off) s[tid] += s[tid + off];
        __syncthreads();
    }
    if (tid == 0) fflag[0] = (s[0] > 2048) ? 1 : 0;
}

// pack edge ids to int32 + fused in-degree count (dst half)
__global__ void g7_pack(const int* raw, const int* iflag, int* ei, int* deg) {
    int i = blockIdx.x * blockDim.x + threadIdx.x;
    if (i < 2 * N_EDGES) {
        int v;
        if (iflag[0] == 0) {
            v = raw[2 * i];
        } else {
            v = raw[i];
        }
        ei[i] = v;
        if (i >= N_EDGES) atomicAdd(&deg[v], 1);
    }
}

// fused weight prep: W1 split (65536) + W2 cvt (8192) + b1 (128) + b2 (64)
__global__ void g7_prep(const void* W1, const void* W2, const void* b1, const void* b2,
                        const int* fflag, unsigned short* W1Th, unsigned short* W1Tl,
                        float* W2f, float* b1f, float* b2f) {
    int i = blockIdx.x * blockDim.x + threadIdx.x;
    int isbf = fflag[0];
    if (i < F_IN * F_HID) {
        int k = i >> 7;
        int n = i & 127;
        float w;
        if (isbf == 1) {
            w = g7_bf2f(((const unsigned short*)W1)[i]);
        } else {
            w = ((const float*)W1)[i];
        }
        unsigned short hi = g7_f2bf(w);
        unsigned short lo = g7_f2bf(w - g7_bf2f(hi));
        W1Th[n * F_IN + k] = hi;
        W1Tl[n * F_IN + k] = lo;
    } else if (i < F_IN * F_HID + F_HID * F_OUT) {
        int j = i - F_IN * F_HID;
        W2f[j] = (isbf == 1) ? g7_bf2f(((const unsigned short*)W2)[j])
                             : ((const float*)W2)[j];
    } else if (i < F_IN * F_HID + F_HID * F_OUT + F_HID) {
        int j = i - F_IN * F_HID - F_HID * F_OUT;
        b1f[j] = (isbf == 1) ? g7_bf2f(((const unsigned short*)b1)[j])
                             : ((const float*)b1)[j];
    } else if (i < F_IN * F_HID + F_HID * F_OUT + F_HID + F_OUT) {
        int j = i - F_IN * F_HID - F_HID * F_OUT - F_HID;
        b2f[j] = (isbf == 1) ? g7_bf2f(((const unsigned short*)b2)[j])
                             : ((const float*)b2)[j];
    }
}

__global__ void g7_dinv(const int* deg, float* dinv) {
    int i = blockIdx.x * blockDim.x + threadIdx.x;
    if (i < N_NODES) {
        dinv[i] = rsqrtf((float)deg[i] + 1.0f);
    }
}

// ---- CSR rowptr build: block-sums -> parallel scan of 391 block sums -> per-block scan ----
__global__ void g7_bsum(const int* deg, int* bsum) {
    __shared__ int s[256];
    int i = blockIdx.x * 256 + threadIdx.x;
    s[threadIdx.x] = (i < N_NODES) ? deg[i] : 0;
    __syncthreads();
    for (int off = 128; off > 0; off >>= 1) {
        if (threadIdx.x < off) s[threadIdx.x] += s[threadIdx.x + off];
        __syncthreads();
    }
    if (threadIdx.x == 0) bsum[blockIdx.x] = s[0];
}

// parallel Hillis-Steele scan of nblk (<=512) block sums, 1 block x 512 thr
__global__ void g7_bscan(const int* bsum, int* boff, int nblk, int* rowptr) {
    __shared__ int s[512];
    int tid = threadIdx.x;
    int v = (tid < nblk) ? bsum[tid] : 0;
    s[tid] = v;
    __syncthreads();
    for (int off = 1; off < 512; off <<= 1) {
        int t = (tid >= off) ? s[tid - off] : 0;
        __syncthreads();
        s[tid] += t;
        __syncthreads();
    }
    if (tid < nblk) boff[tid] = s[tid] - v;   // exclusive
    if (tid == nblk - 1) rowptr[N_NODES] = s[tid];
}

__global__ void g7_scan(const int* deg, const int* boff, int* rowptr) {
    __shared__ int s[256];
    int i = blockIdx.x * 256 + threadIdx.x;
    int v = (i < N_NODES) ? deg[i] : 0;
    s[threadIdx.x] = v;
    __syncthreads();
    for (int off = 1; off < 256; off <<= 1) {
        int t = (threadIdx.x >= off) ? s[threadIdx.x - off] : 0;
        __syncthreads();
        s[threadIdx.x] += t;
        __syncthreads();
    }
    if (i < N_NODES) {
        rowptr[i] = s[threadIdx.x] - v + boff[blockIdx.x];
    }
}

// init per-bucket cursors from rowptr (bucket b starts at node b*256)
__global__ void g7_binit(const int* rowptr, int* bcur) {
    int b = blockIdx.x * blockDim.x + threadIdx.x;
    if (b < NBUK) bcur[b] = rowptr[b << BSH];
}

// ---- partition pass 1: edges -> bucket-contiguous (src,dst) pairs. ----
#define P1_EPT 32
#define P1_TILE (256 * P1_EPT)   // 8192 edges/block, grid 196
__global__ void g7_part1(const int* ei, int* bcur, uint2* part) {
    __shared__ int cnt[NBUK + 1];
    __shared__ int base[NBUK + 1];
    int tid = threadIdx.x;
    long long t0 = (long long)blockIdx.x * P1_TILE;
    for (int i = tid; i < NBUK; i += 256) cnt[i] = 0;
    __syncthreads();
#pragma unroll 4
    for (int r = 0; r < P1_EPT; ++r) {
        long long e = t0 + r * 256 + tid;
        if (e < N_EDGES) {
            int d = ei[N_EDGES + e];
            atomicAdd(&cnt[d >> BSH], 1);
        }
    }
    __syncthreads();
    for (int i = tid; i < NBUK; i += 256) {
        int c = cnt[i];
        base[i] = (c > 0) ? atomicAdd(&bcur[i], c) : 0;
        cnt[i] = 0;                 // reuse as local cursor
    }
    __syncthreads();
#pragma unroll 4
    for (int r = 0; r < P1_EPT; ++r) {
        long long e = t0 + r * 256 + tid;
        if (e < N_EDGES) {
            int s = ei[e];
            int d = ei[N_EDGES + e];
            int bk = d >> BSH;
            int off = atomicAdd(&cnt[bk], 1);
            uint2 p; p.x = (u32)s; p.y = (u32)d;
            part[(long long)base[bk] + off] = p;
        }
    }
}

// ---- partition pass 2: within-bucket exact scatter via LDS cursors. ----
__global__ void g7_part2(const int* rowptr, const uint2* part, int* csr) {
    __shared__ int lcur[256];
    int b = blockIdx.x;
    int tid = threadIdx.x;
    int n0 = b << BSH;
    int n1 = n0 + 256; if (n1 > N_NODES) n1 = N_NODES;
    if (tid < 256) {
        int node = n0 + tid;
        lcur[tid] = (node < N_NODES) ? rowptr[node] : 0;
    }
    __syncthreads();
    int beg = rowptr[n0];
    int end = rowptr[n1];
    for (int j = beg + tid; j < end; j += 512) {
        uint2 p = part[j];
        int pos = atomicAdd(&lcur[p.y - n0], 1);
        csr[pos] = (int)p.x;
    }
}

// ---- GEMM1 split-bf16 MFMA: h1[100000,128] = x @ W1, fp32-class accuracy.
// 128x128 tile, 512 thr = 8 waves (2x4): wave = 64x32 out, acc = 32 AGPR/lane.
// Double-buffered LDS 64KB, round-5 sync structure. ----
__global__ __launch_bounds__(512, 4) void g7_gemm1s(const void* x, const int* fflag,
        const unsigned short* W1Th, const unsigned short* W1Tl, unsigned short* h1b) {
    __shared__ uint4 smv[4096];          // 64 KB: [A0 16K][B0 16K][A1 16K][B1 16K]
    char* smc = (char*)smv;
    int tid = threadIdx.x;
    int m0 = blockIdx.x * 128;
    int w = tid >> 6;
    int lane = tid & 63;
    int wr = w >> 2, wc = w & 3;         // wave grid 2x4
    int la = lane & 15;                  // mfma row/col within 16
    int lk = lane >> 4;                  // mfma k-group (8 bf16 = 16 B)
    int isbf = fflag[0];
    int ar = tid >> 2;                   // A staging: row 0..127
    int ah = tid & 3;                    // A staging: 8-elem col chunk

    f32x4 acc[4][2];
#pragma unroll
    for (int i = 0; i < 4; ++i)
#pragma unroll
        for (int j = 0; j < 2; ++j) acc[i][j] = (f32x4){0.f, 0.f, 0.f, 0.f};

    uint4 rA[2];                         // 8 fp32 (2x uint4) or 8 bf16 (1x uint4)

    auto loadA = [&](int k0) {
        int m = m0 + ar;
        if (m >= N_NODES) m = N_NODES - 1;   // dup-read, discarded at store
        if (isbf) {
            const char* s = (const char*)x + ((long long)m * F_IN + k0 + ah * 8) * 2;
            rA[0] = *(const uint4*)s;
        } else {
            const char* s = (const char*)x + ((long long)m * F_IN + k0 + ah * 8) * 4;
            rA[0] = *(const uint4*)s;
            rA[1] = *(const uint4*)(s + 16);
        }
    };

    // convert regs -> hi/lo bf16, swizzled ds_write (8 elems/thread)
    auto writeA = [&](char* As) {
        float f[8];
        if (isbf) {
            const unsigned short* p = (const unsigned short*)&rA[0];
#pragma unroll
            for (int j = 0; j < 8; ++j) f[j] = g7_bf2f(p[j]);
        } else {
            const float* p = (const float*)rA;
#pragma unroll
            for (int j = 0; j < 8; ++j) f[j] = p[j];
        }
        unsigned int hw[4], lw[4];
#pragma unroll
        for (int j = 0; j < 4; ++j) {
            unsigned short h0 = g7_f2bf(f[2 * j]);
            unsigned short h1v = g7_f2bf(f[2 * j + 1]);
            unsigned short l0 = g7_f2bf(f[2 * j] - g7_bf2f(h0));
            unsigned short l1 = g7_f2bf(f[2 * j + 1] - g7_bf2f(h1v));
            hw[j] = (unsigned int)h0 | ((unsigned int)h1v << 16);
            lw[j] = (unsigned int)l0 | ((unsigned int)l1 << 16);
        }
        int swz = (ar & 7) << 4;
        char* dst = As + ar * 128;
        *(uint4*)(dst + ((ah * 16) ^ swz))      = make_uint4(hw[0], hw[1], hw[2], hw[3]);
        *(uint4*)(dst + ((64 + ah * 16) ^ swz)) = make_uint4(lw[0], lw[1], lw[2], lw[3]);
    };

    // B-tile: rows n 0..127 (16 per wave), 128B = [hi|lo] swizzle-permuted,
    // linear LDS dest + inverse-swizzled per-lane global source
    auto stageB = [&](char* Bs, int k0) {
#pragma unroll
        for (int p = 0; p < 2; ++p) {
            int nr = w * 16 + p * 8 + (lane >> 3);
            int cp = ((lane & 7) * 16) ^ (((lane >> 3) & 7) << 4);  // byte col in [0,128)
            const char* src = (cp < 64)
                ? (const char*)W1Th + (long long)nr * 1024 + k0 * 2 + cp
                : (const char*)W1Tl + (long long)nr * 1024 + k0 * 2 + (cp - 64);
            g7_gl2lds16(src, Bs + (w * 16 + p * 8) * 128);
        }
    };

    auto compute = [&](const char* As, const char* Bs) {
        bf16x8 bh[2], bl[2];
#pragma unroll
        for (int j = 0; j < 2; ++j) {
            int n = wc * 32 + j * 16 + la;
            int swzb = (n & 7) << 4;
            const char* bb = Bs + n * 128;
            bh[j] = *(const bf16x8*)(bb + ((lk * 16) ^ swzb));
            bl[j] = *(const bf16x8*)(bb + ((64 + lk * 16) ^ swzb));
        }
#pragma unroll
        for (int i = 0; i < 4; ++i) {
            int r = wr * 64 + i * 16 + la;
            int swz = (r & 7) << 4;
            const char* ab = As + r * 128;
            bf16x8 ah_ = *(const bf16x8*)(ab + ((lk * 16) ^ swz));
            bf16x8 al_ = *(const bf16x8*)(ab + ((64 + lk * 16) ^ swz));
#pragma unroll
            for (int j = 0; j < 2; ++j) {
                acc[i][j] = __builtin_amdgcn_mfma_f32_16x16x32_bf16(
                    ah_, bh[j], acc[i][j], 0, 0, 0);
                acc[i][j] = __builtin_amdgcn_mfma_f32_16x16x32_bf16(
                    al_, bh[j], acc[i][j], 0, 0, 0);
                acc[i][j] = __builtin_amdgcn_mfma_f32_16x16x32_bf16(
                    ah_, bl[j], acc[i][j], 0, 0, 0);
            }
        }
    };

    // prologue: stage K-step 0 into buffer 0
    loadA(0);
    stageB(smc + 16384, 0);
    writeA(smc);
    __syncthreads();                      // drains vmcnt: buf0 ready

    for (int kt = 0; kt < 16; ++kt) {
        char* bc = smc + (kt & 1) * 32768;
        char* bn = smc + ((kt & 1) ^ 1) * 32768;
        if (kt < 15) {                    // issue next-tile loads early (T14)
            loadA((kt + 1) * 32);
            stageB(bn + 16384, (kt + 1) * 32);
        }
        compute(bc, bc + 16384);
        if (kt < 15) writeA(bn);          // convert-late: vmcnt wait lands here
        __syncthreads();
    }

    // epilogue: D row = lk*4+q (m), col = la (n) per 16x16 fragment; bf16 store
#pragma unroll
    for (int i = 0; i < 4; ++i) {
#pragma unroll
        for (int j = 0; j < 2; ++j) {
            int n = wc * 32 + j * 16 + la;
#pragma unroll
            for (int q = 0; q < 4; ++q) {
                int m = m0 + wr * 64 + i * 16 + lk * 4 + q;
                if (m < N_NODES) {
                    h1b[(long long)m * F_HID + n] = g7_f2bf(acc[i][j][q]);
                }
            }
        }
    }
}

// ---- agg1: quarter-wave per edge (16 lanes x uint4 = 256B row), 4 groups x
// 2-unroll = 8 gathers in flight. Lane fl owns features 8fl..8fl+7.
// Reduce via shfl_xor(16,32); group 0 writes. r1 = relu(di*acc + b1), fp32. ----
__global__ void g7_agg1(const int* rowptr, const int* csr, const float* dinv,
                        const unsigned short* h1b, const float* b1, float* r1) {
    int node = blockIdx.x * 4 + (threadIdx.x >> 6);
    int lane = threadIdx.x & 63;
    int g = lane >> 4;
    int fl = lane & 15;
    if (node >= N_NODES) return;
    int beg = rowptr[node];
    int end = rowptr[node + 1];
    const uint4* hv = (const uint4*)h1b;   // row = 16 uint4
    float a[8];
#pragma unroll
    for (int t = 0; t < 8; ++t) a[t] = 0.f;
    int j = beg + g;
    for (; j + 4 < end; j += 8) {
        int s0 = csr[j];
        int s1 = csr[j + 4];
        float w0 = dinv[s0];
        float w1 = dinv[s1];
        uint4 v0 = hv[(long long)s0 * 16 + fl];
        uint4 v1 = hv[(long long)s1 * 16 + fl];
        float2 p;
        p = g7_up(v0.x); a[0] += p.x * w0; a[1] += p.y * w0;
        p = g7_up(v0.y); a[2] += p.x * w0; a[3] += p.y * w0;
        p = g7_up(v0.z); a[4] += p.x * w0; a[5] += p.y * w0;
        p = g7_up(v0.w); a[6] += p.x * w0; a[7] += p.y * w0;
        p = g7_up(v1.x); a[0] += p.x * w1; a[1] += p.y * w1;
        p = g7_up(v1.y); a[2] += p.x * w1; a[3] += p.y * w1;
        p = g7_up(v1.z); a[4] += p.x * w1; a[5] += p.y * w1;
        p = g7_up(v1.w); a[6] += p.x * w1; a[7] += p.y * w1;
    }
    if (j < end) {
        int s0 = csr[j];
        float w0 = dinv[s0];
        uint4 v0 = hv[(long long)s0 * 16 + fl];
        float2 p;
        p = g7_up(v0.x); a[0] += p.x * w0; a[1] += p.y * w0;
        p = g7_up(v0.y); a[2] += p.x * w0; a[3] += p.y * w0;
        p = g7_up(v0.z); a[4] += p.x * w0; a[5] += p.y * w0;
        p = g7_up(v0.w); a[6] += p.x * w0; a[7] += p.y * w0;
    }
    float di = dinv[node];
    if (g == 0) {                     // self-loop as an edge with w = dinv[node]
        uint4 vd = hv[(long long)node * 16 + fl];
        float2 p;
        p = g7_up(vd.x); a[0] += p.x * di; a[1] += p.y * di;
        p = g7_up(vd.y); a[2] += p.x * di; a[3] += p.y * di;
        p = g7_up(vd.z); a[4] += p.x * di; a[5] += p.y * di;
        p = g7_up(vd.w); a[6] += p.x * di; a[7] += p.y * di;
    }
#pragma unroll
    for (int t = 0; t < 8; ++t) {
        a[t] += __shfl_xor(a[t], 16);
        a[t] += __shfl_xor(a[t], 32);
    }
    if (g == 0) {
        float4 b0 = *(const float4*)(b1 + 8 * fl);
        float4 b1v = *(const float4*)(b1 + 8 * fl + 4);
        float o[8];
        o[0] = a[0] * di + b0.x; o[1] = a[1] * di + b0.y;
        o[2] = a[2] * di + b0.z; o[3] = a[3] * di + b0.w;
        o[4] = a[4] * di + b1v.x; o[5] = a[5] * di + b1v.y;
        o[6] = a[6] * di + b1v.z; o[7] = a[7] * di + b1v.w;
#pragma unroll
        for (int t = 0; t < 8; ++t) if (o[t] < 0.f) o[t] = 0.f;
        float* dst = r1 + (long long)node * F_HID + 8 * fl;
        float4 s0; s0.x = o[0]; s0.y = o[1]; s0.z = o[2]; s0.w = o[3];
        float4 s1; s1.x = o[4]; s1.y = o[5]; s1.z = o[6]; s1.w = o[7];
        *(float4*)dst = s0;
        *(float4*)(dst + 4) = s1;
    }
}

// ---- GEMM2: h2b[100000,64] (bf16) = r1 @ W2f. BM=64, BN=64, BK=32, 256 thr ----
__global__ void g7_gemm2(const float* r1, const float* W2, unsigned short* h2b) {
    __shared__ float Rs[32][68];
    __shared__ float Ws[32][64];
    int tid = threadIdx.x;
    int m0 = blockIdx.x * 64;
    int tx = tid & 15;
    int ty = tid >> 4;
    float acc[4][4];
#pragma unroll
    for (int i = 0; i < 4; ++i) {
#pragma unroll
        for (int j = 0; j < 4; ++j) acc[i][j] = 0.0f;
    }

    for (int k0 = 0; k0 < F_HID; k0 += 32) {
#pragma unroll
        for (int r = 0; r < 8; ++r) {
            int i = r * 256 + tid;
            int kk = i & 31;
            int mm = i >> 5;
            int m = m0 + mm;
            float v = 0.0f;
            if (m < N_NODES) {
                v = r1[(long long)m * F_HID + k0 + kk];
            }
            Rs[kk][mm] = v;
        }
#pragma unroll
        for (int r = 0; r < 8; ++r) {
            int i = r * 256 + tid;
            int wk = i >> 6;
            int wn = i & 63;
            Ws[wk][wn] = W2[(k0 + wk) * F_OUT + wn];
        }
        __syncthreads();
#pragma unroll
        for (int k = 0; k < 32; ++k) {
            float a[4];
            float b[4];
#pragma unroll
            for (int i = 0; i < 4; ++i) a[i] = Rs[k][ty * 4 + i];
#pragma unroll
            for (int j = 0; j < 4; ++j) b[j] = Ws[k][tx * 4 + j];
#pragma unroll
            for (int i = 0; i < 4; ++i) {
#pragma unroll
                for (int j = 0; j < 4; ++j) acc[i][j] += a[i] * b[j];
            }
        }
        __syncthreads();
    }
#pragma unroll
    for (int i = 0; i < 4; ++i) {
        int m = m0 + ty * 4 + i;
        if (m < N_NODES) {
            unsigned int w0 = (unsigned int)g7_f2bf(acc[i][0])
                            | ((unsigned int)g7_f2bf(acc[i][1]) << 16);
            unsigned int w1 = (unsigned int)g7_f2bf(acc[i][2])
                            | ((unsigned int)g7_f2bf(acc[i][3]) << 16);
            uint2 o; o.x = w0; o.y = w1;
            *(uint2*)(h2b + (long long)m * F_OUT + tx * 4) = o;
        }
    }
}

// ---- agg2: eighth-wave per edge (8 lanes x uint4 = 128B row), 8 groups x
// 2-unroll = 16 gathers in flight. Lane fl owns features 8fl..8fl+7.
// Reduce via shfl_xor(8,16,32); group 0 writes (input float format). ----
__global__ void g7_agg2(const int* rowptr, const int* csr, const float* dinv,
                        const unsigned short* h2b, const float* b2, const int* fflag,
                        void* out) {
    int node = blockIdx.x * 4 + (threadIdx.x >> 6);
    int lane = threadIdx.x & 63;
    int g = lane >> 3;
    int fl = lane & 7;
    if (node >= N_NODES) return;
    int beg = rowptr[node];
    int end = rowptr[node + 1];
    const uint4* hv = (const uint4*)h2b;   // row = 8 uint4
    float a[8];
#pragma unroll
    for (int t = 0; t < 8; ++t) a[t] = 0.f;
    int j = beg + g;
    for (; j + 8 < end; j += 16) {
        int s0 = csr[j];
        int s1 = csr[j + 8];
        float w0 = dinv[s0];
        float w1 = dinv[s1];
        uint4 v0 = hv[(long long)s0 * 8 + fl];
        uint4 v1 = hv[(long long)s1 * 8 + fl];
        float2 p;
        p = g7_up(v0.x); a[0] += p.x * w0; a[1] += p.y * w0;
        p = g7_up(v0.y); a[2] += p.x * w0; a[3] += p.y * w0;
        p = g7_up(v0.z); a[4] += p.x * w0; a[5] += p.y * w0;
        p = g7_up(v0.w); a[6] += p.x * w0; a[7] += p.y * w0;
        p = g7_up(v1.x); a[0] += p.x * w1; a[1] += p.y * w1;
        p = g7_up(v1.y); a[2] += p.x * w1; a[3] += p.y * w1;
        p = g7_up(v1.z); a[4] += p.x * w1; a[5] += p.y * w1;
        p = g7_up(v1.w); a[6] += p.x * w1; a[7] += p.y * w1;
    }
    if (j < end) {
        int s0 = csr[j];
        float w0 = dinv[s0];
        uint4 v0 = hv[(long long)s0 * 8 + fl];
        float2 p;
        p = g7_up(v0.x); a[0] += p.x * w0; a[1] += p.y * w0;
        p = g7_up(v0.y); a[2] += p.x * w0; a[3] += p.y * w0;
        p = g7_up(v0.z); a[4] += p.x * w0; a[5] += p.y * w0;
        p = g7_up(v0.w); a[6] += p.x * w0; a[7] += p.y * w0;
    }
    float di = dinv[node];
    if (g == 0) {
        uint4 vd = hv[(long long)node * 8 + fl];
        float2 p;
        p = g7_up(vd.x); a[0] += p.x * di; a[1] += p.y * di;
        p = g7_up(vd.y); a[2] += p.x * di; a[3] += p.y * di;
        p = g7_up(vd.z); a[4] += p.x * di; a[5] += p.y * di;
        p = g7_up(vd.w); a[6] += p.x * di; a[7] += p.y * di;
    }
#pragma unroll
    for (int t = 0; t < 8; ++t) {
        a[t] += __shfl_xor(a[t], 8);
        a[t] += __shfl_xor(a[t], 16);
        a[t] += __shfl_xor(a[t], 32);
    }
    if (g == 0) {
        float o[8];
#pragma unroll
        for (int t = 0; t < 8; ++t) o[t] = a[t] * di + b2[8 * fl + t];
        long long oi = (long long)node * F_OUT + 8 * fl;
        if (fflag[0] == 1) {
            unsigned int w0 = (u32)g7_f2bf(o[0]) | ((u32)g7_f2bf(o[1]) << 16);
            unsigned int w1 = (u32)g7_f2bf(o[2]) | ((u32)g7_f2bf(o[3]) << 16);
            unsigned int w2 = (u32)g7_f2bf(o[4]) | ((u32)g7_f2bf(o[5]) << 16);
            unsigned int w3 = (u32)g7_f2bf(o[6]) | ((u32)g7_f2bf(o[7]) << 16);
            *(uint4*)((unsigned short*)out + oi) = make_uint4(w0, w1, w2, w3);
        } else {
            float* dst = (float*)out + oi;
            float4 s0; s0.x = o[0]; s0.y = o[1]; s0.z = o[2]; s0.w = o[3];
            float4 s1; s1.x = o[4]; s1.y = o[5]; s1.z = o[6]; s1.w = o[7];
            *(float4*)dst = s0;
            *(float4*)(dst + 4) = s1;
        }
    }
}

extern "C" void kernel_launch(void* const* d_in, const int* in_sizes, int n_in,
                              void* d_out, int out_size, void* d_ws, size_t ws_size,
                              hipStream_t stream) {
    const void* x     = d_in[0];
    const int* ei_raw = (const int*)d_in[1];
    const void* W1    = d_in[2];
    const void* b1    = d_in[3];
    const void* W2    = d_in[4];
    const void* b2    = d_in[5];

    const int NBLK = (N_NODES + 255) / 256;   // 391

    // workspace layout (byte offsets, 16B-aligned):
    char* ws = (char*)d_ws;
    int*   deg    = (int*)(ws + 0);            //    400,000 B
    int*   iflag  = (int*)(ws + 409600);       //          4 B
    int*   fflag  = (int*)(ws + 409616);       //          4 B
    int*   bsum   = (int*)(ws + 409632);       //      1,564 B
    int*   boff   = (int*)(ws + 412800);       //      1,564 B
    int*   bcur   = (int*)(ws + 450560);       //      1,564 B
    float* dinv   = (float*)(ws + 524288);     //    400,000 B
    unsigned short* W1Th = (unsigned short*)(ws + 1048576); // 131,072 B
    unsigned short* W1Tl = (unsigned short*)(ws + 1179648); // 131,072 B
    float* b1f    = (float*)(ws + 1310720);    //        512 B
    float* W2f    = (float*)(ws + 1311232);    //     32,768 B
    float* b2f    = (float*)(ws + 1344000);    //        256 B
    int*   ei     = (int*)(ws + 2097152);      // 12,800,000 B
    int*   rowptr = (int*)(ws + 14897152);     //    400,004 B
    int*   csr    = (int*)(ws + 16777216);     //  6,400,000 B
    unsigned short* h1b = (unsigned short*)(ws + 23177216); // 25,600,000 B
    uint2* part   = (uint2*)(ws + 50331648);   // 12,800,000 B
    float* r1     = (float*)(ws + 74377216);   // 51,200,000 B
    unsigned short* h2b = (unsigned short*)(ws + 125577216); // 12,800,000 B

    g7_zero<<<(N_NODES + 255) / 256, 256, 0, stream>>>(deg, N_NODES);

    g7_iprobe<<<1, 256, 0, stream>>>(ei_raw, iflag);
    g7_fprobe<<<1, 256, 0, stream>>>((const unsigned int*)x, fflag);

    // pack + fused degree count
    g7_pack<<<(2 * N_EDGES + 255) / 256, 256, 0, stream>>>(ei_raw, iflag, ei, deg);

    // fused weight prep (W1 split + W2/b1/b2 cvt)
    const int PREP_N = F_IN * F_HID + F_HID * F_OUT + F_HID + F_OUT;
    g7_prep<<<(PREP_N + 255) / 256, 256, 0, stream>>>(W1, W2, b1, b2, fflag,
                                                      W1Th, W1Tl, W2f, b1f, b2f);

    g7_dinv<<<(N_NODES + 255) / 256, 256, 0, stream>>>(deg, dinv);

    // CSR rowptr
    g7_bsum<<<NBLK, 256, 0, stream>>>(deg, bsum);
    g7_bscan<<<1, 512, 0, stream>>>(bsum, boff, NBLK, rowptr);
    g7_scan<<<NBLK, 256, 0, stream>>>(deg, boff, rowptr);

    // two-pass bucket partition (replaces direct scatter)
    g7_binit<<<(NBUK + 255) / 256, 256, 0, stream>>>(rowptr, bcur);
    g7_part1<<<(N_EDGES + P1_TILE - 1) / P1_TILE, 256, 0, stream>>>(ei, bcur, part);
    g7_part2<<<NBUK, 512, 0, stream>>>(rowptr, part, csr);

    // GEMM1: split-bf16 MFMA (fp32-class accuracy), bf16 output table
    g7_gemm1s<<<(N_NODES + 127) / 128, 512, 0, stream>>>(x, fflag, W1Th, W1Tl, h1b);

    g7_agg1<<<N_NODES / 4, 256, 0, stream>>>(rowptr, csr, dinv, h1b, b1f, r1);

    g7_gemm2<<<(N_NODES + 63) / 64, 256, 0, stream>>>(r1, W2f, h2b);

    g7_agg2<<<N_NODES / 4, 256, 0, stream>>>(rowptr, csr, dinv, h2b, b2f, fflag, d_out);
}

// Round 9
// 588.034 us; speedup vs baseline: 1.2461x; 1.0362x over previous
//
#include <hip/hip_runtime.h>

#define N_NODES 100000
#define N_EDGES 1600000
#define F_IN 512
#define F_HID 128
#define F_OUT 64

#define BSH 8                      // bucket = dst >> 8 (256 nodes / bucket)
#define NBUK 391                   // ceil(100000/256)

typedef unsigned int u32;
typedef __attribute__((ext_vector_type(8))) short bf16x8;
typedef __attribute__((ext_vector_type(4))) float f32x4;

__device__ float g7_bf2f(unsigned short u) {
    return __uint_as_float(((unsigned int)u) << 16);
}

__device__ unsigned short g7_f2bf(float f) {
    unsigned int u = __float_as_uint(f);
    u = u + 0x7fffu + ((u >> 16) & 1u);
    return (unsigned short)(u >> 16);
}

// unpack a u32 of 2 packed bf16 -> (lo, hi) floats
__device__ float2 g7_up(unsigned int u) {
    float2 r;
    r.x = __uint_as_float(u << 16);
    r.y = __uint_as_float(u & 0xffff0000u);
    return r;
}

__device__ static inline void g7_gl2lds16(const void* g, void* l) {
    __builtin_amdgcn_global_load_lds(
        (const __attribute__((address_space(1))) u32*)g,
        (__attribute__((address_space(3))) u32*)l, 16, 0, 0);
}

__global__ void GCN_16716012716713_kernel() {}

__global__ void g7_zero(int* p, int n) {
    int i = blockIdx.x * blockDim.x + threadIdx.x;
    if (i < n) p[i] = 0;
}

// edge_index dtype probe: 1=int32, 0=int64 (int64 has all-zero high words).
__global__ void g7_iprobe(const int* raw, int* iflag) {
    __shared__ int s[256];
    int tid = threadIdx.x;
    int f = 0;
    for (int i = tid; i < 1024; i += 256) {
        if (raw[2 * i + 1] != 0) f = 1;
    }
    s[tid] = f;
    __syncthreads();
    for (int off = 128; off > 0; off >>= 1) {
        if (tid < off) s[tid] |= s[tid + off];
        __syncthreads();
    }
    if (tid == 0) iflag[0] = s[0];
}

// float dtype probe on x: 1=bf16, 0=fp32.
__global__ void g7_fprobe(const unsigned int* xw, int* fflag) {
    __shared__ int s[256];
    int tid = threadIdx.x;
    int cnt = 0;
    for (int i = tid; i < 4096; i += 256) {
        unsigned int lo = xw[i] & 0xffffu;
        unsigned int e = (lo >> 7) & 0xffu;
        if (e >= 110u && e <= 140u) cnt = cnt + 1;
    }
    s[tid] = cnt;
    __syncthreads();
    for (int off = 128; off > 0; off >>= 1) {
        if (tid < off) s[tid] += s[tid + off];
        __syncthreads();
    }
    if (tid == 0) fflag[0] = (s[0] > 2048) ? 1 : 0;
}

// pack edge ids to int32 + fused in-degree count (dst half)
__global__ void g7_pack(const int* raw, const int* iflag, int* ei, int* deg) {
    int i = blockIdx.x * blockDim.x + threadIdx.x;
    if (i < 2 * N_EDGES) {
        int v;
        if (iflag[0] == 0) {
            v = raw[2 * i];
        } else {
            v = raw[i];
        }
        ei[i] = v;
        if (i >= N_EDGES) atomicAdd(&deg[v], 1);
    }
}

// fused weight prep: W1 split (65536, [n][k]) + W2 split (8192, [n][k]) + b1 + b2
__global__ void g7_prep(const void* W1, const void* W2, const void* b1, const void* b2,
                        const int* fflag, unsigned short* W1Th, unsigned short* W1Tl,
                        unsigned short* W2Th, unsigned short* W2Tl,
                        float* b1f, float* b2f) {
    int i = blockIdx.x * blockDim.x + threadIdx.x;
    int isbf = fflag[0];
    if (i < F_IN * F_HID) {
        int k = i >> 7;
        int n = i & 127;
        float w;
        if (isbf == 1) {
            w = g7_bf2f(((const unsigned short*)W1)[i]);
        } else {
            w = ((const float*)W1)[i];
        }
        unsigned short hi = g7_f2bf(w);
        unsigned short lo = g7_f2bf(w - g7_bf2f(hi));
        W1Th[n * F_IN + k] = hi;
        W1Tl[n * F_IN + k] = lo;
    } else if (i < F_IN * F_HID + F_HID * F_OUT) {
        int j = i - F_IN * F_HID;
        int k = j >> 6;          // 0..127
        int n = j & 63;          // 0..63
        float w;
        if (isbf == 1) {
            w = g7_bf2f(((const unsigned short*)W2)[j]);
        } else {
            w = ((const float*)W2)[j];
        }
        unsigned short hi = g7_f2bf(w);
        unsigned short lo = g7_f2bf(w - g7_bf2f(hi));
        W2Th[n * F_HID + k] = hi;
        W2Tl[n * F_HID + k] = lo;
    } else if (i < F_IN * F_HID + F_HID * F_OUT + F_HID) {
        int j = i - F_IN * F_HID - F_HID * F_OUT;
        b1f[j] = (isbf == 1) ? g7_bf2f(((const unsigned short*)b1)[j])
                             : ((const float*)b1)[j];
    } else if (i < F_IN * F_HID + F_HID * F_OUT + F_HID + F_OUT) {
        int j = i - F_IN * F_HID - F_HID * F_OUT - F_HID;
        b2f[j] = (isbf == 1) ? g7_bf2f(((const unsigned short*)b2)[j])
                             : ((const float*)b2)[j];
    }
}

__global__ void g7_dinv(const int* deg, float* dinv) {
    int i = blockIdx.x * blockDim.x + threadIdx.x;
    if (i < N_NODES) {
        dinv[i] = rsqrtf((float)deg[i] + 1.0f);
    }
}

// ---- CSR rowptr build: block-sums -> parallel scan of 391 block sums -> per-block scan ----
__global__ void g7_bsum(const int* deg, int* bsum) {
    __shared__ int s[256];
    int i = blockIdx.x * 256 + threadIdx.x;
    s[threadIdx.x] = (i < N_NODES) ? deg[i] : 0;
    __syncthreads();
    for (int off = 128; off > 0; off >>= 1) {
        if (threadIdx.x < off) s[threadIdx.x] += s[threadIdx.x + off];
        __syncthreads();
    }
    if (threadIdx.x == 0) bsum[blockIdx.x] = s[0];
}

// parallel Hillis-Steele scan of nblk (<=512) block sums, 1 block x 512 thr
__global__ void g7_bscan(const int* bsum, int* boff, int nblk, int* rowptr) {
    __shared__ int s[512];
    int tid = threadIdx.x;
    int v = (tid < nblk) ? bsum[tid] : 0;
    s[tid] = v;
    __syncthreads();
    for (int off = 1; off < 512; off <<= 1) {
        int t = (tid >= off) ? s[tid - off] : 0;
        __syncthreads();
        s[tid] += t;
        __syncthreads();
    }
    if (tid < nblk) boff[tid] = s[tid] - v;   // exclusive
    if (tid == nblk - 1) rowptr[N_NODES] = s[tid];
}

__global__ void g7_scan(const int* deg, const int* boff, int* rowptr) {
    __shared__ int s[256];
    int i = blockIdx.x * 256 + threadIdx.x;
    int v = (i < N_NODES) ? deg[i] : 0;
    s[threadIdx.x] = v;
    __syncthreads();
    for (int off = 1; off < 256; off <<= 1) {
        int t = (threadIdx.x >= off) ? s[threadIdx.x - off] : 0;
        __syncthreads();
        s[threadIdx.x] += t;
        __syncthreads();
    }
    if (i < N_NODES) {
        rowptr[i] = s[threadIdx.x] - v + boff[blockIdx.x];
    }
}

// init per-bucket cursors from rowptr (bucket b starts at node b*256)
__global__ void g7_binit(const int* rowptr, int* bcur) {
    int b = blockIdx.x * blockDim.x + threadIdx.x;
    if (b < NBUK) bcur[b] = rowptr[b << BSH];
}

// ---- partition pass 1: edges -> bucket-contiguous (src,dst) pairs. ----
#define P1_EPT 32
#define P1_TILE (256 * P1_EPT)   // 8192 edges/block, grid 196
__global__ void g7_part1(const int* ei, int* bcur, uint2* part) {
    __shared__ int cnt[NBUK + 1];
    __shared__ int base[NBUK + 1];
    int tid = threadIdx.x;
    long long t0 = (long long)blockIdx.x * P1_TILE;
    for (int i = tid; i < NBUK; i += 256) cnt[i] = 0;
    __syncthreads();
#pragma unroll 4
    for (int r = 0; r < P1_EPT; ++r) {
        long long e = t0 + r * 256 + tid;
        if (e < N_EDGES) {
            int d = ei[N_EDGES + e];
            atomicAdd(&cnt[d >> BSH], 1);
        }
    }
    __syncthreads();
    for (int i = tid; i < NBUK; i += 256) {
        int c = cnt[i];
        base[i] = (c > 0) ? atomicAdd(&bcur[i], c) : 0;
        cnt[i] = 0;                 // reuse as local cursor
    }
    __syncthreads();
#pragma unroll 4
    for (int r = 0; r < P1_EPT; ++r) {
        long long e = t0 + r * 256 + tid;
        if (e < N_EDGES) {
            int s = ei[e];
            int d = ei[N_EDGES + e];
            int bk = d >> BSH;
            int off = atomicAdd(&cnt[bk], 1);
            uint2 p; p.x = (u32)s; p.y = (u32)d;
            part[(long long)base[bk] + off] = p;
        }
    }
}

// ---- partition pass 2: within-bucket exact scatter via LDS cursors. ----
__global__ void g7_part2(const int* rowptr, const uint2* part, int* csr) {
    __shared__ int lcur[256];
    int b = blockIdx.x;
    int tid = threadIdx.x;
    int n0 = b << BSH;
    int n1 = n0 + 256; if (n1 > N_NODES) n1 = N_NODES;
    if (tid < 256) {
        int node = n0 + tid;
        lcur[tid] = (node < N_NODES) ? rowptr[node] : 0;
    }
    __syncthreads();
    int beg = rowptr[n0];
    int end = rowptr[n1];
    for (int j = beg + tid; j < end; j += 512) {
        uint2 p = part[j];
        int pos = atomicAdd(&lcur[p.y - n0], 1);
        csr[pos] = (int)p.x;
    }
}

// ---- GEMM1 split-bf16 MFMA: h1[100000,128] = x @ W1, fp32-class accuracy.
// 128x128 tile, 512 thr = 8 waves (2x4): wave = 64x32 out, acc = 32 AGPR/lane.
// Double-buffered LDS 64KB, round-5 sync structure. ----
__global__ __launch_bounds__(512, 4) void g7_gemm1s(const void* x, const int* fflag,
        const unsigned short* W1Th, const unsigned short* W1Tl, unsigned short* h1b) {
    __shared__ uint4 smv[4096];          // 64 KB: [A0 16K][B0 16K][A1 16K][B1 16K]
    char* smc = (char*)smv;
    int tid = threadIdx.x;
    int m0 = blockIdx.x * 128;
    int w = tid >> 6;
    int lane = tid & 63;
    int wr = w >> 2, wc = w & 3;         // wave grid 2x4
    int la = lane & 15;                  // mfma row/col within 16
    int lk = lane >> 4;                  // mfma k-group (8 bf16 = 16 B)
    int isbf = fflag[0];
    int ar = tid >> 2;                   // A staging: row 0..127
    int ah = tid & 3;                    // A staging: 8-elem col chunk

    f32x4 acc[4][2];
#pragma unroll
    for (int i = 0; i < 4; ++i)
#pragma unroll
        for (int j = 0; j < 2; ++j) acc[i][j] = (f32x4){0.f, 0.f, 0.f, 0.f};

    uint4 rA[2];                         // 8 fp32 (2x uint4) or 8 bf16 (1x uint4)

    auto loadA = [&](int k0) {
        int m = m0 + ar;
        if (m >= N_NODES) m = N_NODES - 1;   // dup-read, discarded at store
        if (isbf) {
            const char* s = (const char*)x + ((long long)m * F_IN + k0 + ah * 8) * 2;
            rA[0] = *(const uint4*)s;
        } else {
            const char* s = (const char*)x + ((long long)m * F_IN + k0 + ah * 8) * 4;
            rA[0] = *(const uint4*)s;
            rA[1] = *(const uint4*)(s + 16);
        }
    };

    // convert regs -> hi/lo bf16, swizzled ds_write (8 elems/thread)
    auto writeA = [&](char* As) {
        float f[8];
        if (isbf) {
            const unsigned short* p = (const unsigned short*)&rA[0];
#pragma unroll
            for (int j = 0; j < 8; ++j) f[j] = g7_bf2f(p[j]);
        } else {
            const float* p = (const float*)rA;
#pragma unroll
            for (int j = 0; j < 8; ++j) f[j] = p[j];
        }
        unsigned int hw[4], lw[4];
#pragma unroll
        for (int j = 0; j < 4; ++j) {
            unsigned short h0 = g7_f2bf(f[2 * j]);
            unsigned short h1v = g7_f2bf(f[2 * j + 1]);
            unsigned short l0 = g7_f2bf(f[2 * j] - g7_bf2f(h0));
            unsigned short l1 = g7_f2bf(f[2 * j + 1] - g7_bf2f(h1v));
            hw[j] = (unsigned int)h0 | ((unsigned int)h1v << 16);
            lw[j] = (unsigned int)l0 | ((unsigned int)l1 << 16);
        }
        int swz = (ar & 7) << 4;
        char* dst = As + ar * 128;
        *(uint4*)(dst + ((ah * 16) ^ swz))      = make_uint4(hw[0], hw[1], hw[2], hw[3]);
        *(uint4*)(dst + ((64 + ah * 16) ^ swz)) = make_uint4(lw[0], lw[1], lw[2], lw[3]);
    };

    // B-tile: rows n 0..127 (16 per wave), 128B = [hi|lo] swizzle-permuted,
    // linear LDS dest + inverse-swizzled per-lane global source
    auto stageB = [&](char* Bs, int k0) {
#pragma unroll
        for (int p = 0; p < 2; ++p) {
            int nr = w * 16 + p * 8 + (lane >> 3);
            int cp = ((lane & 7) * 16) ^ (((lane >> 3) & 7) << 4);  // byte col in [0,128)
            const char* src = (cp < 64)
                ? (const char*)W1Th + (long long)nr * 1024 + k0 * 2 + cp
                : (const char*)W1Tl + (long long)nr * 1024 + k0 * 2 + (cp - 64);
            g7_gl2lds16(src, Bs + (w * 16 + p * 8) * 128);
        }
    };

    auto compute = [&](const char* As, const char* Bs) {
        bf16x8 bh[2], bl[2];
#pragma unroll
        for (int j = 0; j < 2; ++j) {
            int n = wc * 32 + j * 16 + la;
            int swzb = (n & 7) << 4;
            const char* bb = Bs + n * 128;
            bh[j] = *(const bf16x8*)(bb + ((lk * 16) ^ swzb));
            bl[j] = *(const bf16x8*)(bb + ((64 + lk * 16) ^ swzb));
        }
#pragma unroll
        for (int i = 0; i < 4; ++i) {
            int r = wr * 64 + i * 16 + la;
            int swz = (r & 7) << 4;
            const char* ab = As + r * 128;
            bf16x8 ah_ = *(const bf16x8*)(ab + ((lk * 16) ^ swz));
            bf16x8 al_ = *(const bf16x8*)(ab + ((64 + lk * 16) ^ swz));
#pragma unroll
            for (int j = 0; j < 2; ++j) {
                acc[i][j] = __builtin_amdgcn_mfma_f32_16x16x32_bf16(
                    ah_, bh[j], acc[i][j], 0, 0, 0);
                acc[i][j] = __builtin_amdgcn_mfma_f32_16x16x32_bf16(
                    al_, bh[j], acc[i][j], 0, 0, 0);
                acc[i][j] = __builtin_amdgcn_mfma_f32_16x16x32_bf16(
                    ah_, bl[j], acc[i][j], 0, 0, 0);
            }
        }
    };

    // prologue: stage K-step 0 into buffer 0
    loadA(0);
    stageB(smc + 16384, 0);
    writeA(smc);
    __syncthreads();                      // drains vmcnt: buf0 ready

    for (int kt = 0; kt < 16; ++kt) {
        char* bc = smc + (kt & 1) * 32768;
        char* bn = smc + ((kt & 1) ^ 1) * 32768;
        if (kt < 15) {                    // issue next-tile loads early (T14)
            loadA((kt + 1) * 32);
            stageB(bn + 16384, (kt + 1) * 32);
        }
        compute(bc, bc + 16384);
        if (kt < 15) writeA(bn);          // convert-late: vmcnt wait lands here
        __syncthreads();
    }

    // epilogue: D row = lk*4+q (m), col = la (n) per 16x16 fragment; bf16 store
#pragma unroll
    for (int i = 0; i < 4; ++i) {
#pragma unroll
        for (int j = 0; j < 2; ++j) {
            int n = wc * 32 + j * 16 + la;
#pragma unroll
            for (int q = 0; q < 4; ++q) {
                int m = m0 + wr * 64 + i * 16 + lk * 4 + q;
                if (m < N_NODES) {
                    h1b[(long long)m * F_HID + n] = g7_f2bf(acc[i][j][q]);
                }
            }
        }
    }
}

// ---- agg1: quarter-wave per edge (16 lanes x uint4 = 256B row), 4 groups x
// 2-unroll = 8 gathers in flight. Lane fl owns features 8fl..8fl+7. ----
__global__ void g7_agg1(const int* rowptr, const int* csr, const float* dinv,
                        const unsigned short* h1b, const float* b1, float* r1) {
    int node = blockIdx.x * 4 + (threadIdx.x >> 6);
    int lane = threadIdx.x & 63;
    int g = lane >> 4;
    int fl = lane & 15;
    if (node >= N_NODES) return;
    int beg = rowptr[node];
    int end = rowptr[node + 1];
    const uint4* hv = (const uint4*)h1b;   // row = 16 uint4
    float a[8];
#pragma unroll
    for (int t = 0; t < 8; ++t) a[t] = 0.f;
    int j = beg + g;
    for (; j + 4 < end; j += 8) {
        int s0 = csr[j];
        int s1 = csr[j + 4];
        float w0 = dinv[s0];
        float w1 = dinv[s1];
        uint4 v0 = hv[(long long)s0 * 16 + fl];
        uint4 v1 = hv[(long long)s1 * 16 + fl];
        float2 p;
        p = g7_up(v0.x); a[0] += p.x * w0; a[1] += p.y * w0;
        p = g7_up(v0.y); a[2] += p.x * w0; a[3] += p.y * w0;
        p = g7_up(v0.z); a[4] += p.x * w0; a[5] += p.y * w0;
        p = g7_up(v0.w); a[6] += p.x * w0; a[7] += p.y * w0;
        p = g7_up(v1.x); a[0] += p.x * w1; a[1] += p.y * w1;
        p = g7_up(v1.y); a[2] += p.x * w1; a[3] += p.y * w1;
        p = g7_up(v1.z); a[4] += p.x * w1; a[5] += p.y * w1;
        p = g7_up(v1.w); a[6] += p.x * w1; a[7] += p.y * w1;
    }
    if (j < end) {
        int s0 = csr[j];
        float w0 = dinv[s0];
        uint4 v0 = hv[(long long)s0 * 16 + fl];
        float2 p;
        p = g7_up(v0.x); a[0] += p.x * w0; a[1] += p.y * w0;
        p = g7_up(v0.y); a[2] += p.x * w0; a[3] += p.y * w0;
        p = g7_up(v0.z); a[4] += p.x * w0; a[5] += p.y * w0;
        p = g7_up(v0.w); a[6] += p.x * w0; a[7] += p.y * w0;
    }
    float di = dinv[node];
    if (g == 0) {                     // self-loop as an edge with w = dinv[node]
        uint4 vd = hv[(long long)node * 16 + fl];
        float2 p;
        p = g7_up(vd.x); a[0] += p.x * di; a[1] += p.y * di;
        p = g7_up(vd.y); a[2] += p.x * di; a[3] += p.y * di;
        p = g7_up(vd.z); a[4] += p.x * di; a[5] += p.y * di;
        p = g7_up(vd.w); a[6] += p.x * di; a[7] += p.y * di;
    }
#pragma unroll
    for (int t = 0; t < 8; ++t) {
        a[t] += __shfl_xor(a[t], 16);
        a[t] += __shfl_xor(a[t], 32);
    }
    if (g == 0) {
        float4 b0 = *(const float4*)(b1 + 8 * fl);
        float4 b1v = *(const float4*)(b1 + 8 * fl + 4);
        float o[8];
        o[0] = a[0] * di + b0.x; o[1] = a[1] * di + b0.y;
        o[2] = a[2] * di + b0.z; o[3] = a[3] * di + b0.w;
        o[4] = a[4] * di + b1v.x; o[5] = a[5] * di + b1v.y;
        o[6] = a[6] * di + b1v.z; o[7] = a[7] * di + b1v.w;
#pragma unroll
        for (int t = 0; t < 8; ++t) if (o[t] < 0.f) o[t] = 0.f;
        float* dst = r1 + (long long)node * F_HID + 8 * fl;
        float4 s0; s0.x = o[0]; s0.y = o[1]; s0.z = o[2]; s0.w = o[3];
        float4 s1; s1.x = o[4]; s1.y = o[5]; s1.z = o[6]; s1.w = o[7];
        *(float4*)dst = s0;
        *(float4*)(dst + 4) = s1;
    }
}

// ---- GEMM2 split-bf16 MFMA: h2b[100000,64] = r1 @ W2, fp32-class accuracy.
// 128x64 tile, 256 thr = 4 waves (2x2): wave = 64x32 out, acc = 32 AGPR.
// K=128, 4 K-steps of 32; LDS 48KB double-buffered ([A 16K][B 8K] x2). ----
__global__ __launch_bounds__(256, 2) void g7_gemm2m(const float* r1,
        const unsigned short* W2Th, const unsigned short* W2Tl, unsigned short* h2b) {
    __shared__ uint4 smv[3072];          // 48 KB
    char* smc = (char*)smv;
    int tid = threadIdx.x;
    int m0 = blockIdx.x * 128;
    int w = tid >> 6;
    int lane = tid & 63;
    int wr = w >> 1, wc = w & 1;         // wave grid 2x2
    int la = lane & 15;
    int lk = lane >> 4;
    int ar = tid >> 1;                   // A staging: row 0..127
    int ah = tid & 1;                    // A staging: 16-elem half

    f32x4 acc[4][2];
#pragma unroll
    for (int i = 0; i < 4; ++i)
#pragma unroll
        for (int j = 0; j < 2; ++j) acc[i][j] = (f32x4){0.f, 0.f, 0.f, 0.f};

    uint4 rA[4];                         // 16 fp32

    auto loadA = [&](int k0) {
        int m = m0 + ar;
        if (m >= N_NODES) m = N_NODES - 1;
        const char* s = (const char*)(r1 + (long long)m * F_HID + k0 + ah * 16);
        rA[0] = *(const uint4*)s;
        rA[1] = *(const uint4*)(s + 16);
        rA[2] = *(const uint4*)(s + 32);
        rA[3] = *(const uint4*)(s + 48);
    };

    auto writeA = [&](char* As) {
        const float* f = (const float*)rA;
        unsigned int hw[8], lw[8];
#pragma unroll
        for (int j = 0; j < 8; ++j) {
            unsigned short h0 = g7_f2bf(f[2 * j]);
            unsigned short h1v = g7_f2bf(f[2 * j + 1]);
            unsigned short l0 = g7_f2bf(f[2 * j] - g7_bf2f(h0));
            unsigned short l1 = g7_f2bf(f[2 * j + 1] - g7_bf2f(h1v));
            hw[j] = (unsigned int)h0 | ((unsigned int)h1v << 16);
            lw[j] = (unsigned int)l0 | ((unsigned int)l1 << 16);
        }
        int swz = (ar & 7) << 4;
        char* dst = As + ar * 128;
        *(uint4*)(dst + ((ah * 32 + 0) ^ swz))      = make_uint4(hw[0], hw[1], hw[2], hw[3]);
        *(uint4*)(dst + ((ah * 32 + 16) ^ swz))     = make_uint4(hw[4], hw[5], hw[6], hw[7]);
        *(uint4*)(dst + ((64 + ah * 32 + 0) ^ swz)) = make_uint4(lw[0], lw[1], lw[2], lw[3]);
        *(uint4*)(dst + ((64 + ah * 32 + 16) ^ swz))= make_uint4(lw[4], lw[5], lw[6], lw[7]);
    };

    // B: rows n 0..63 (16/wave), 128B = [hi|lo] swizzled; W2T row = 256 B
    auto stageB = [&](char* Bs, int k0) {
#pragma unroll
        for (int p = 0; p < 2; ++p) {
            int nr = w * 16 + p * 8 + (lane >> 3);
            int cp = ((lane & 7) * 16) ^ (((lane >> 3) & 7) << 4);
            const char* src = (cp < 64)
                ? (const char*)W2Th + (long long)nr * 256 + k0 * 2 + cp
                : (const char*)W2Tl + (long long)nr * 256 + k0 * 2 + (cp - 64);
            g7_gl2lds16(src, Bs + (w * 16 + p * 8) * 128);
        }
    };

    auto compute = [&](const char* As, const char* Bs) {
        bf16x8 bh[2], bl[2];
#pragma unroll
        for (int j = 0; j < 2; ++j) {
            int n = wc * 32 + j * 16 + la;
            int swzb = (n & 7) << 4;
            const char* bb = Bs + n * 128;
            bh[j] = *(const bf16x8*)(bb + ((lk * 16) ^ swzb));
            bl[j] = *(const bf16x8*)(bb + ((64 + lk * 16) ^ swzb));
        }
#pragma unroll
        for (int i = 0; i < 4; ++i) {
            int r = wr * 64 + i * 16 + la;
            int swz = (r & 7) << 4;
            const char* ab = As + r * 128;
            bf16x8 ah_ = *(const bf16x8*)(ab + ((lk * 16) ^ swz));
            bf16x8 al_ = *(const bf16x8*)(ab + ((64 + lk * 16) ^ swz));
#pragma unroll
            for (int j = 0; j < 2; ++j) {
                acc[i][j] = __builtin_amdgcn_mfma_f32_16x16x32_bf16(
                    ah_, bh[j], acc[i][j], 0, 0, 0);
                acc[i][j] = __builtin_amdgcn_mfma_f32_16x16x32_bf16(
                    al_, bh[j], acc[i][j], 0, 0, 0);
                acc[i][j] = __builtin_amdgcn_mfma_f32_16x16x32_bf16(
                    ah_, bl[j], acc[i][j], 0, 0, 0);
            }
        }
    };

    loadA(0);
    stageB(smc + 16384, 0);
    writeA(smc);
    __syncthreads();

    for (int kt = 0; kt < 4; ++kt) {
        char* bc = smc + (kt & 1) * 24576;
        char* bn = smc + ((kt & 1) ^ 1) * 24576;
        if (kt < 3) {
            loadA((kt + 1) * 32);
            stageB(bn + 16384, (kt + 1) * 32);
        }
        compute(bc, bc + 16384);
        if (kt < 3) writeA(bn);
        __syncthreads();
    }

#pragma unroll
    for (int i = 0; i < 4; ++i) {
#pragma unroll
        for (int j = 0; j < 2; ++j) {
            int n = wc * 32 + j * 16 + la;
#pragma unroll
            for (int q = 0; q < 4; ++q) {
                int m = m0 + wr * 64 + i * 16 + lk * 4 + q;
                if (m < N_NODES) {
                    h2b[(long long)m * F_OUT + n] = g7_f2bf(acc[i][j][q]);
                }
            }
        }
    }
}

// ---- agg2: eighth-wave per edge (8 lanes x uint4 = 128B row), 8 groups x
// 2-unroll = 16 gathers in flight. Lane fl owns features 8fl..8fl+7. ----
__global__ void g7_agg2(const int* rowptr, const int* csr, const float* dinv,
                        const unsigned short* h2b, const float* b2, const int* fflag,
                        void* out) {
    int node = blockIdx.x * 4 + (threadIdx.x >> 6);
    int lane = threadIdx.x & 63;
    int g = lane >> 3;
    int fl = lane & 7;
    if (node >= N_NODES) return;
    int beg = rowptr[node];
    int end = rowptr[node + 1];
    const uint4* hv = (const uint4*)h2b;   // row = 8 uint4
    float a[8];
#pragma unroll
    for (int t = 0; t < 8; ++t) a[t] = 0.f;
    int j = beg + g;
    for (; j + 8 < end; j += 16) {
        int s0 = csr[j];
        int s1 = csr[j + 8];
        float w0 = dinv[s0];
        float w1 = dinv[s1];
        uint4 v0 = hv[(long long)s0 * 8 + fl];
        uint4 v1 = hv[(long long)s1 * 8 + fl];
        float2 p;
        p = g7_up(v0.x); a[0] += p.x * w0; a[1] += p.y * w0;
        p = g7_up(v0.y); a[2] += p.x * w0; a[3] += p.y * w0;
        p = g7_up(v0.z); a[4] += p.x * w0; a[5] += p.y * w0;
        p = g7_up(v0.w); a[6] += p.x * w0; a[7] += p.y * w0;
        p = g7_up(v1.x); a[0] += p.x * w1; a[1] += p.y * w1;
        p = g7_up(v1.y); a[2] += p.x * w1; a[3] += p.y * w1;
        p = g7_up(v1.z); a[4] += p.x * w1; a[5] += p.y * w1;
        p = g7_up(v1.w); a[6] += p.x * w1; a[7] += p.y * w1;
    }
    if (j < end) {
        int s0 = csr[j];
        float w0 = dinv[s0];
        uint4 v0 = hv[(long long)s0 * 8 + fl];
        float2 p;
        p = g7_up(v0.x); a[0] += p.x * w0; a[1] += p.y * w0;
        p = g7_up(v0.y); a[2] += p.x * w0; a[3] += p.y * w0;
        p = g7_up(v0.z); a[4] += p.x * w0; a[5] += p.y * w0;
        p = g7_up(v0.w); a[6] += p.x * w0; a[7] += p.y * w0;
    }
    float di = dinv[node];
    if (g == 0) {
        uint4 vd = hv[(long long)node * 8 + fl];
        float2 p;
        p = g7_up(vd.x); a[0] += p.x * di; a[1] += p.y * di;
        p = g7_up(vd.y); a[2] += p.x * di; a[3] += p.y * di;
        p = g7_up(vd.z); a[4] += p.x * di; a[5] += p.y * di;
        p = g7_up(vd.w); a[6] += p.x * di; a[7] += p.y * di;
    }
#pragma unroll
    for (int t = 0; t < 8; ++t) {
        a[t] += __shfl_xor(a[t], 8);
        a[t] += __shfl_xor(a[t], 16);
        a[t] += __shfl_xor(a[t], 32);
    }
    if (g == 0) {
        float o[8];
#pragma unroll
        for (int t = 0; t < 8; ++t) o[t] = a[t] * di + b2[8 * fl + t];
        long long oi = (long long)node * F_OUT + 8 * fl;
        if (fflag[0] == 1) {
            unsigned int w0 = (u32)g7_f2bf(o[0]) | ((u32)g7_f2bf(o[1]) << 16);
            unsigned int w1 = (u32)g7_f2bf(o[2]) | ((u32)g7_f2bf(o[3]) << 16);
            unsigned int w2 = (u32)g7_f2bf(o[4]) | ((u32)g7_f2bf(o[5]) << 16);
            unsigned int w3 = (u32)g7_f2bf(o[6]) | ((u32)g7_f2bf(o[7]) << 16);
            *(uint4*)((unsigned short*)out + oi) = make_uint4(w0, w1, w2, w3);
        } else {
            float* dst = (float*)out + oi;
            float4 s0; s0.x = o[0]; s0.y = o[1]; s0.z = o[2]; s0.w = o[3];
            float4 s1; s1.x = o[4]; s1.y = o[5]; s1.z = o[6]; s1.w = o[7];
            *(float4*)dst = s0;
            *(float4*)(dst + 4) = s1;
        }
    }
}

extern "C" void kernel_launch(void* const* d_in, const int* in_sizes, int n_in,
                              void* d_out, int out_size, void* d_ws, size_t ws_size,
                              hipStream_t stream) {
    const void* x     = d_in[0];
    const int* ei_raw = (const int*)d_in[1];
    const void* W1    = d_in[2];
    const void* b1    = d_in[3];
    const void* W2    = d_in[4];
    const void* b2    = d_in[5];

    const int NBLK = (N_NODES + 255) / 256;   // 391

    // workspace layout (byte offsets, 16B-aligned):
    char* ws = (char*)d_ws;
    int*   deg    = (int*)(ws + 0);            //    400,000 B
    int*   iflag  = (int*)(ws + 409600);       //          4 B
    int*   fflag  = (int*)(ws + 409616);       //          4 B
    int*   bsum   = (int*)(ws + 409632);       //      1,564 B
    int*   boff   = (int*)(ws + 412800);       //      1,564 B
    int*   bcur   = (int*)(ws + 450560);       //      1,564 B
    float* dinv   = (float*)(ws + 524288);     //    400,000 B
    unsigned short* W1Th = (unsigned short*)(ws + 1048576); // 131,072 B
    unsigned short* W1Tl = (unsigned short*)(ws + 1179648); // 131,072 B
    float* b1f    = (float*)(ws + 1310720);    //        512 B
    unsigned short* W2Th = (unsigned short*)(ws + 1311232); // 16,384 B
    unsigned short* W2Tl = (unsigned short*)(ws + 1327616); // 16,384 B
    float* b2f    = (float*)(ws + 1344000);    //        256 B
    int*   ei     = (int*)(ws + 2097152);      // 12,800,000 B
    int*   rowptr = (int*)(ws + 14897152);     //    400,004 B
    int*   csr    = (int*)(ws + 16777216);     //  6,400,000 B
    unsigned short* h1b = (unsigned short*)(ws + 23177216); // 25,600,000 B
    uint2* part   = (uint2*)(ws + 50331648);   // 12,800,000 B
    float* r1     = (float*)(ws + 74377216);   // 51,200,000 B
    unsigned short* h2b = (unsigned short*)(ws + 125577216); // 12,800,000 B

    g7_zero<<<(N_NODES + 255) / 256, 256, 0, stream>>>(deg, N_NODES);

    g7_iprobe<<<1, 256, 0, stream>>>(ei_raw, iflag);
    g7_fprobe<<<1, 256, 0, stream>>>((const unsigned int*)x, fflag);

    // pack + fused degree count
    g7_pack<<<(2 * N_EDGES + 255) / 256, 256, 0, stream>>>(ei_raw, iflag, ei, deg);

    // fused weight prep (W1 split + W2 split + b1/b2 cvt)
    const int PREP_N = F_IN * F_HID + F_HID * F_OUT + F_HID + F_OUT;
    g7_prep<<<(PREP_N + 255) / 256, 256, 0, stream>>>(W1, W2, b1, b2, fflag,
                                                      W1Th, W1Tl, W2Th, W2Tl, b1f, b2f);

    g7_dinv<<<(N_NODES + 255) / 256, 256, 0, stream>>>(deg, dinv);

    // CSR rowptr
    g7_bsum<<<NBLK, 256, 0, stream>>>(deg, bsum);
    g7_bscan<<<1, 512, 0, stream>>>(bsum, boff, NBLK, rowptr);
    g7_scan<<<NBLK, 256, 0, stream>>>(deg, boff, rowptr);

    // two-pass bucket partition (replaces direct scatter)
    g7_binit<<<(NBUK + 255) / 256, 256, 0, stream>>>(rowptr, bcur);
    g7_part1<<<(N_EDGES + P1_TILE - 1) / P1_TILE, 256, 0, stream>>>(ei, bcur, part);
    g7_part2<<<NBUK, 512, 0, stream>>>(rowptr, part, csr);

    // GEMM1: split-bf16 MFMA (fp32-class accuracy), bf16 output table
    g7_gemm1s<<<(N_NODES + 127) / 128, 512, 0, stream>>>(x, fflag, W1Th, W1Tl, h1b);

    g7_agg1<<<N_NODES / 4, 256, 0, stream>>>(rowptr, csr, dinv, h1b, b1f, r1);

    // GEMM2: split-bf16 MFMA
    g7_gemm2m<<<(N_NODES + 127) / 128, 256, 0, stream>>>(r1, W2Th, W2Tl, h2b);

    g7_agg2<<<N_NODES / 4, 256, 0, stream>>>(rowptr, csr, dinv, h2b, b2f, fflag, d_out);
}